// Round 9
// baseline (602.997 us; speedup 1.0000x reference)
//
#include <hip/hip_runtime.h>

#define HW    4096
#define WIMG  64
#define CIN   256
#define C3    768
#define COUT  256
#define BATCH 16
#define NHB   32
#define EPS_F 1e-5f
#define QSCALE 1024.0f   // pow2: exactly undone in epilogue

typedef __attribute__((ext_vector_type(8))) short    short8;
typedef __attribute__((ext_vector_type(8))) _Float16 half8;
typedef __attribute__((ext_vector_type(4))) float    floatx4;

__device__ inline short f32_to_bf16(float f) {
    unsigned u = __builtin_bit_cast(unsigned, f);
    unsigned r = u + 0x7fffu + ((u >> 16) & 1u);
    return (short)(r >> 16);
}
__device__ inline float bf16_to_f32(short s) {
    return __builtin_bit_cast(float, ((unsigned)(unsigned short)s) << 16);
}

// ---------------------------------------------------------------------------
// K1a v2: q channels (packed 256) of qkv 1x1 conv, f32 VALU GEMM.
// 128x128 tile, 8x8 per thread. q stays f32 (eps-denominator cliff: relu
// leak x ksum/eps amplification forbids low-precision q).
// v2: (1) Ws row stride 128->132 — staging-write banks (4k+c)%32 cover all
// banks 2x/wave (was 16-way conflict, 18% of cycles); rows stay 16B-aligned.
// (2) register double-buffer: next K-slice global loads issued right after
// the staging barrier, overlapping the 16x64-FMA compute phase.
// ---------------------------------------------------------------------------
__global__ __launch_bounds__(256) void conv_q_f32(
    const float* __restrict__ in,     // (B, 256, HW)
    const float* __restrict__ w,      // (768, 256)
    const float* __restrict__ scale,
    const float* __restrict__ bias,
    float* __restrict__ Qf)           // (B, 256, HW) packed q
{
    const int pt  = blockIdx.x * 128;
    const int ct  = blockIdx.y * 128;
    const int b   = blockIdx.z;
    const int tid = threadIdx.x;
    const int tx  = tid & 15;         // px groups tx*4 and 64+tx*4
    const int ty  = tid >> 4;         // ch groups ty*4 and 64+ty*4

    __shared__ float Ws[16][132];     // padded: conflict-free staging writes
    __shared__ float Xs[16][128];

    float acc[8][8] = {};
    const float* xb = in + (size_t)b * CIN * HW + pt;

    float wreg[8], xreg[8];
    // prologue: preload K-slice 0
    #pragma unroll
    for (int i = 0; i < 8; i++) {
        int idx = tid + i * 256;
        int c = idx >> 4, k = idx & 15;
        int cp = ct + c;
        int creal = (cp >> 3) * 24 + (cp & 7);
        wreg[i] = w[(size_t)creal * CIN + k];
    }
    #pragma unroll
    for (int i = 0; i < 8; i++) {
        int idx = tid + i * 256;
        int k = idx >> 7, p = idx & 127;
        xreg[i] = xb[(size_t)k * HW + p];
    }

    for (int k0 = 0; k0 < CIN; k0 += 16) {
        __syncthreads();              // previous compute done reading LDS
        #pragma unroll
        for (int i = 0; i < 8; i++) {
            int idx = tid + i * 256;
            Ws[idx & 15][idx >> 4] = wreg[i];
        }
        #pragma unroll
        for (int i = 0; i < 8; i++) {
            int idx = tid + i * 256;
            Xs[idx >> 7][idx & 127] = xreg[i];
        }
        __syncthreads();

        if (k0 + 16 < CIN) {          // prefetch next slice under compute
            #pragma unroll
            for (int i = 0; i < 8; i++) {
                int idx = tid + i * 256;
                int c = idx >> 4, k = idx & 15;
                int cp = ct + c;
                int creal = (cp >> 3) * 24 + (cp & 7);
                wreg[i] = w[(size_t)creal * CIN + k0 + 16 + k];
            }
            #pragma unroll
            for (int i = 0; i < 8; i++) {
                int idx = tid + i * 256;
                int k = idx >> 7, p = idx & 127;
                xreg[i] = xb[(size_t)(k0 + 16 + k) * HW + p];
            }
        }

        #pragma unroll
        for (int kk = 0; kk < 16; kk++) {
            float4 a0 = *reinterpret_cast<const float4*>(&Ws[kk][ty * 4]);
            float4 a1 = *reinterpret_cast<const float4*>(&Ws[kk][64 + ty * 4]);
            float4 b0 = *reinterpret_cast<const float4*>(&Xs[kk][tx * 4]);
            float4 b1 = *reinterpret_cast<const float4*>(&Xs[kk][64 + tx * 4]);
            float a[8] = {a0.x, a0.y, a0.z, a0.w, a1.x, a1.y, a1.z, a1.w};
            float bb[8] = {b0.x, b0.y, b0.z, b0.w, b1.x, b1.y, b1.z, b1.w};
            #pragma unroll
            for (int i = 0; i < 8; i++)
                #pragma unroll
                for (int j = 0; j < 8; j++)
                    acc[i][j] += a[i] * bb[j];
        }
    }

    #pragma unroll
    for (int i = 0; i < 8; i++) {
        int cp = ct + (i < 4 ? ty * 4 + i : 64 + ty * 4 + (i - 4));
        int creal = (cp >> 3) * 24 + (cp & 7);
        float s = scale[creal];
        float bi = bias[creal];
        float4 v0, v1;
        v0.x = fmaxf(acc[i][0] * s + bi, 0.f);
        v0.y = fmaxf(acc[i][1] * s + bi, 0.f);
        v0.z = fmaxf(acc[i][2] * s + bi, 0.f);
        v0.w = fmaxf(acc[i][3] * s + bi, 0.f);
        v1.x = fmaxf(acc[i][4] * s + bi, 0.f);
        v1.y = fmaxf(acc[i][5] * s + bi, 0.f);
        v1.z = fmaxf(acc[i][6] * s + bi, 0.f);
        v1.w = fmaxf(acc[i][7] * s + bi, 0.f);
        float* dst = Qf + ((size_t)b * 256 + cp) * HW + pt;
        *reinterpret_cast<float4*>(dst + tx * 4)      = v0;
        *reinterpret_cast<float4*>(dst + 64 + tx * 4) = v1;
    }
}

// ---------------------------------------------------------------------------
// K1b: k/v channels (packed 512) via bf16 hi/lo 3-pass MFMA (~f32 accurate).
// Packed c' in [0,512): real = (c'>>4)*24 + 8 + (c'&15). Out f32.
// ---------------------------------------------------------------------------
__global__ __launch_bounds__(256) void conv_kv_mfma(
    const float* __restrict__ x,
    const float* __restrict__ w,
    const float* __restrict__ scale,
    const float* __restrict__ bias,
    float* __restrict__ KV)           // (B, 512, HW) packed k/v, f32
{
    const int ct = blockIdx.x, pt = blockIdx.y, b = blockIdx.z;
    const int tid  = threadIdx.x;
    const int wv   = tid >> 6, lane = tid & 63;
    const int u    = lane & 15, q8 = (lane >> 4) * 8;
    const int chb  = ct * 128 + (wv >> 1) * 64;
    const int pxb  = pt * 128 + (wv & 1) * 64;

    floatx4 acc[4][4];
    #pragma unroll
    for (int i = 0; i < 4; i++)
        #pragma unroll
        for (int j = 0; j < 4; j++) acc[i][j] = (floatx4)0.f;

    for (int kc = 0; kc < 8; kc++) {
        const int k0 = kc * 32 + q8;
        short8 ahi[4], alo[4];
        #pragma unroll
        for (int mt = 0; mt < 4; mt++) {
            int cp = chb + mt * 16 + u;
            int creal = (cp >> 4) * 24 + 8 + (cp & 15);
            const float* wp = w + (size_t)creal * CIN + k0;
            #pragma unroll
            for (int j = 0; j < 8; j++) {
                float f = wp[j];
                short h = f32_to_bf16(f);
                ahi[mt][j] = h;
                alo[mt][j] = f32_to_bf16(f - bf16_to_f32(h));
            }
        }
        short8 bhi[4], blo[4];
        #pragma unroll
        for (int nt = 0; nt < 4; nt++) {
            const float* xp = x + ((size_t)b * CIN + k0) * HW + pxb + nt * 16 + u;
            #pragma unroll
            for (int j = 0; j < 8; j++) {
                float f = xp[(size_t)j * HW];
                short h = f32_to_bf16(f);
                bhi[nt][j] = h;
                blo[nt][j] = f32_to_bf16(f - bf16_to_f32(h));
            }
        }
        #pragma unroll
        for (int mt = 0; mt < 4; mt++)
            #pragma unroll
            for (int nt = 0; nt < 4; nt++) {
                acc[mt][nt] = __builtin_amdgcn_mfma_f32_16x16x32_bf16(ahi[mt], bhi[nt], acc[mt][nt], 0, 0, 0);
                acc[mt][nt] = __builtin_amdgcn_mfma_f32_16x16x32_bf16(ahi[mt], blo[nt], acc[mt][nt], 0, 0, 0);
                acc[mt][nt] = __builtin_amdgcn_mfma_f32_16x16x32_bf16(alo[mt], bhi[nt], acc[mt][nt], 0, 0, 0);
            }
    }

    const int quad = lane >> 4;
    #pragma unroll
    for (int mt = 0; mt < 4; mt++)
        #pragma unroll
        for (int r = 0; r < 4; r++) {
            int cp = chb + mt * 16 + quad * 4 + r;
            int creal = (cp >> 4) * 24 + 8 + (cp & 15);
            float s = scale[creal], bi = bias[creal];
            #pragma unroll
            for (int nt = 0; nt < 4; nt++) {
                int px = pxb + nt * 16 + u;
                KV[((size_t)b * 512 + cp) * HW + px] = fmaxf(acc[mt][nt][r] * s + bi, 0.f);
            }
        }
}

// ---------------------------------------------------------------------------
// K0z: zero the stats region (atomic consumers below; re-entrant per launch).
// ---------------------------------------------------------------------------
__global__ __launch_bounds__(256) void zero_stats(float* __restrict__ stats)
{
    int i = blockIdx.x * 256 + threadIdx.x;
    if (i < BATCH * 64 * 72) stats[i] = 0.f;
}

// ---------------------------------------------------------------------------
// K2 v6: stats heads 0..31 via MFMA GRAM. Lane (c=lane&15, kg=lane>>4)
// streams 8 px of channel c per 32-px step; same short8 is both A-row c and
// B-col c of mfma_f32_16x16x32_bf16 -> D = Gram (16x16); rows 8..15 x cols
// 0..7 = vk. ksum via B=ones MFMA. bf16 hi/lo 3-pass ~f32. No LDS/barriers.
// grid (32 h, 4 ps, 16 b) = 2048 blocks.
// ---------------------------------------------------------------------------
__global__ __launch_bounds__(256) void attn_stats_direct(
    const float* __restrict__ KV,
    float* __restrict__ stats)
{
    const int h = blockIdx.x, ps = blockIdx.y, b = blockIdx.z;
    const int tid = threadIdx.x;
    const int lane = tid & 63, wv = tid >> 6;
    const int c  = lane & 15;
    const int kg = lane >> 4;

    const float* cb = KV + ((size_t)b * 512 + h * 16 + c) * HW
                    + ps * 1024 + wv * 256 + kg * 8;

    floatx4 accg = (floatx4)0.f;     // gram
    floatx4 accs = (floatx4)0.f;     // rowsums (ksum in rows 0..7)
    short8 ones;
    #pragma unroll
    for (int j = 0; j < 8; j++) ones[j] = (short)0x3F80;  // bf16 1.0

    for (int st = 0; st < 8; st++) {
        float4 f0 = *reinterpret_cast<const float4*>(cb + st * 32);
        float4 f1 = *reinterpret_cast<const float4*>(cb + st * 32 + 4);
        float v[8] = {f0.x, f0.y, f0.z, f0.w, f1.x, f1.y, f1.z, f1.w};
        short8 hi, lo;
        #pragma unroll
        for (int j = 0; j < 8; j++) {
            short hh = f32_to_bf16(v[j]);
            hi[j] = hh;
            lo[j] = f32_to_bf16(v[j] - bf16_to_f32(hh));
        }
        accg = __builtin_amdgcn_mfma_f32_16x16x32_bf16(hi, hi, accg, 0, 0, 0);
        accg = __builtin_amdgcn_mfma_f32_16x16x32_bf16(hi, lo, accg, 0, 0, 0);
        accg = __builtin_amdgcn_mfma_f32_16x16x32_bf16(lo, hi, accg, 0, 0, 0);
        accs = __builtin_amdgcn_mfma_f32_16x16x32_bf16(hi, ones, accs, 0, 0, 0);
        accs = __builtin_amdgcn_mfma_f32_16x16x32_bf16(lo, ones, accs, 0, 0, 0);
    }

    // D layout: col = lane&15, row = (lane>>4)*4 + r
    float* sb = stats + ((size_t)b * 64 + h) * 72;
    if (c < 8 && kg >= 2) {           // rows 8..15 (v), cols 0..7 (k)
        #pragma unroll
        for (int r = 0; r < 4; r++)
            atomicAdd(sb + ((kg - 2) * 4 + r) * 8 + c, accg[r]);
    }
    if (c == 0 && kg < 2) {           // ksum rows 0..7, any col -> col 0
        #pragma unroll
        for (int r = 0; r < 4; r++)
            atomicAdd(sb + 64 + kg * 4 + r, accs[r]);
    }
}

// ---------------------------------------------------------------------------
// K3 v7: stats heads 32..63 = rolling-window 5x5 dwconv fused with MFMA GRAM.
// Each input row is loaded ONCE (12 rows/strip) and scattered into the <=5
// live output-row accumulators out[5][8] (rotating slots, full unroll ->
// compile-time indices). When input li lands, output li-4 completes ->
// affine -> relu(k) -> bf16 hi/lo -> 5 Gram/ksum MFMAs -> slot reset.
// No LDS, no barriers. grid (32 hp, 2 ysb, 16 b) = 1024 blocks.
// ---------------------------------------------------------------------------
__global__ __launch_bounds__(256) void attn_stats_dw(
    const float* __restrict__ KV,
    const float* __restrict__ dww, const float* __restrict__ dwb,
    const float* __restrict__ pww, const float* __restrict__ pwb,
    float* __restrict__ stats)
{
    const int hp = blockIdx.x, ysb = blockIdx.y, b = blockIdx.z;
    const int tid = threadIdx.x;
    const int lane = tid & 63, wv = tid >> 6;
    const int c  = lane & 15;
    const int kg = lane >> 4;
    const int creal = hp * 24 + 8 + c;

    float wt[25];
    #pragma unroll
    for (int i = 0; i < 25; i++) wt[i] = dww[creal * 25 + i];
    const float pw = pww[creal];
    const float pb = pw * dwb[creal] + pwb[creal];

    const float* cb = KV + ((size_t)b * 512 + hp * 16 + c) * HW;
    const int ybase = ysb * 32 + wv * 8;

    floatx4 accg = (floatx4)0.f;
    floatx4 accs = (floatx4)0.f;
    short8 ones;
    #pragma unroll
    for (int j = 0; j < 8; j++) ones[j] = (short)0x3F80;

    #pragma unroll
    for (int xh = 0; xh < 2; xh++) {
        const int x0 = xh * 32 + kg * 8;
        const float mL = (x0 == 0)  ? 0.f : 1.f;
        const float mR = (x0 == 56) ? 0.f : 1.f;
        const int colL = (x0 == 0)  ? 0  : x0 - 4;
        const int colR = (x0 == 56) ? 56 : x0 + 8;

        float out[5][8] = {};
        #pragma unroll
        for (int li = 0; li < 12; li++) {
            const int ry = ybase + li - 2;
            float4 Q0 = {0,0,0,0}, Q1 = {0,0,0,0}, Q2 = {0,0,0,0}, Q3 = {0,0,0,0};
            if (ry >= 0 && ry < WIMG) {          // wave-uniform
                const float* rp = cb + ry * WIMG;
                Q0 = *reinterpret_cast<const float4*>(rp + colL);
                Q1 = *reinterpret_cast<const float4*>(rp + x0);
                Q2 = *reinterpret_cast<const float4*>(rp + x0 + 4);
                Q3 = *reinterpret_cast<const float4*>(rp + colR);
            }
            float win[12] = {Q0.z * mL, Q0.w * mL,
                             Q1.x, Q1.y, Q1.z, Q1.w,
                             Q2.x, Q2.y, Q2.z, Q2.w,
                             Q3.x * mR, Q3.y * mR};
            // scatter into live output rows lo = li-4..li
            #pragma unroll
            for (int rr = 0; rr < 5; rr++) {
                const int lo = li - rr;
                if (lo >= 0 && lo < 8) {
                    #pragma unroll
                    for (int kx = 0; kx < 5; kx++) {
                        float w5 = wt[rr * 5 + kx];
                        #pragma unroll
                        for (int j = 0; j < 8; j++)
                            out[lo % 5][j] += w5 * win[j + kx];
                    }
                }
            }
            // finalize completed output row lo = li-4
            const int lod = li - 4;
            if (lod >= 0 && lod < 8) {
                short8 hib, lob;
                #pragma unroll
                for (int j = 0; j < 8; j++) {
                    float v = out[lod % 5][j] * pw + pb;
                    float vr = fmaxf(v, 0.f);
                    v = (c < 8) ? vr : v;        // relu k-channels only
                    short hh = f32_to_bf16(v);
                    hib[j] = hh;
                    lob[j] = f32_to_bf16(v - bf16_to_f32(hh));
                }
                accg = __builtin_amdgcn_mfma_f32_16x16x32_bf16(hib, hib, accg, 0, 0, 0);
                accg = __builtin_amdgcn_mfma_f32_16x16x32_bf16(hib, lob, accg, 0, 0, 0);
                accg = __builtin_amdgcn_mfma_f32_16x16x32_bf16(lob, hib, accg, 0, 0, 0);
                accs = __builtin_amdgcn_mfma_f32_16x16x32_bf16(hib, ones, accs, 0, 0, 0);
                accs = __builtin_amdgcn_mfma_f32_16x16x32_bf16(lob, ones, accs, 0, 0, 0);
                #pragma unroll
                for (int j = 0; j < 8; j++) out[lod % 5][j] = 0.f;
            }
        }
    }

    float* sb = stats + ((size_t)b * 64 + 32 + hp) * 72;
    if (c < 8 && kg >= 2) {
        #pragma unroll
        for (int r = 0; r < 4; r++)
            atomicAdd(sb + ((kg - 2) * 4 + r) * 8 + c, accg[r]);
    }
    if (c == 0 && kg < 2) {
        #pragma unroll
        for (int r = 0; r < 4; r++)
            atomicAdd(sb + 64 + kg * 4 + r, accs[r]);
    }
}

// ---------------------------------------------------------------------------
// K3b v7: Qagg = rolling-window 5x5 dwconv + affine of q channels; each input
// row loaded once, out[5][8] rotating slots, finalize -> 2x float4 store.
// Lane (c=lane&7, g=lane>>3) covers 8 px of channel c; wave = full 64-px row
// x 8 channels. grid (32 hb, 2 ysb, 16 b) = 1024 blocks. Raw out (relu K5).
// ---------------------------------------------------------------------------
__global__ __launch_bounds__(256) void q_dwconv(
    const float* __restrict__ Qf,     // (B,256,HW) packed q
    const float* __restrict__ dww, const float* __restrict__ dwb,
    const float* __restrict__ pww, const float* __restrict__ pwb,
    float* __restrict__ Qagg)         // (B,256,HW) packed dwconv(q)
{
    const int hb = blockIdx.x, ysb = blockIdx.y, b = blockIdx.z;
    const int tid = threadIdx.x;
    const int lane = tid & 63, wv = tid >> 6;
    const int c = lane & 7;
    const int g = lane >> 3;          // 0..7
    const int x0 = g * 8;
    const int creal = hb * 24 + c;

    float wt[25];
    #pragma unroll
    for (int i = 0; i < 25; i++) wt[i] = dww[creal * 25 + i];
    const float pw = pww[creal];
    const float pb = pw * dwb[creal] + pwb[creal];

    const float mL = (x0 == 0)  ? 0.f : 1.f;
    const float mR = (x0 == 56) ? 0.f : 1.f;
    const int colL = (x0 == 0)  ? 0  : x0 - 4;
    const int colR = (x0 == 56) ? 56 : x0 + 8;

    const float* cbase = Qf   + ((size_t)b * 256 + hb * 8 + c) * HW;
    float*       obase = Qagg + ((size_t)b * 256 + hb * 8 + c) * HW;
    const int ybase = ysb * 32 + wv * 8;

    float out[5][8] = {};
    #pragma unroll
    for (int li = 0; li < 12; li++) {
        const int ry = ybase + li - 2;
        float4 Q0 = {0,0,0,0}, Q1 = {0,0,0,0}, Q2 = {0,0,0,0}, Q3 = {0,0,0,0};
        if (ry >= 0 && ry < WIMG) {
            const float* rp = cbase + ry * WIMG;
            Q0 = *reinterpret_cast<const float4*>(rp + colL);
            Q1 = *reinterpret_cast<const float4*>(rp + x0);
            Q2 = *reinterpret_cast<const float4*>(rp + x0 + 4);
            Q3 = *reinterpret_cast<const float4*>(rp + colR);
        }
        float win[12] = {Q0.z * mL, Q0.w * mL,
                         Q1.x, Q1.y, Q1.z, Q1.w,
                         Q2.x, Q2.y, Q2.z, Q2.w,
                         Q3.x * mR, Q3.y * mR};
        #pragma unroll
        for (int rr = 0; rr < 5; rr++) {
            const int lo = li - rr;
            if (lo >= 0 && lo < 8) {
                #pragma unroll
                for (int kx = 0; kx < 5; kx++) {
                    float w5 = wt[rr * 5 + kx];
                    #pragma unroll
                    for (int j = 0; j < 8; j++)
                        out[lo % 5][j] += w5 * win[j + kx];
                }
            }
        }
        const int lod = li - 4;
        if (lod >= 0 && lod < 8) {
            float4 o0 = {out[lod % 5][0] * pw + pb, out[lod % 5][1] * pw + pb,
                         out[lod % 5][2] * pw + pb, out[lod % 5][3] * pw + pb};
            float4 o1 = {out[lod % 5][4] * pw + pb, out[lod % 5][5] * pw + pb,
                         out[lod % 5][6] * pw + pb, out[lod % 5][7] * pw + pb};
            float* dst = obase + (ybase + lod) * WIMG + x0;
            *reinterpret_cast<float4*>(dst)     = o0;
            *reinterpret_cast<float4*>(dst + 4) = o1;
            #pragma unroll
            for (int j = 0; j < 8; j++) out[lod % 5][j] = 0.f;
        }
    }
}

// ---------------------------------------------------------------------------
// K4 v2: fold proj weights with vk, COLUMN-RESCALED by g_e = ksum_e + eps.
// Parallelized over head-groups: grid (8 hg, 16 b) = 128 blocks.
// ---------------------------------------------------------------------------
__global__ __launch_bounds__(256) void build_M(
    const float* __restrict__ stats,   // (B,64,72)
    const float* __restrict__ projw,   // (256,512)
    _Float16* __restrict__ Mhi,        // (B,256,512)
    _Float16* __restrict__ Mlo)
{
    const int hg = blockIdx.x;         // head group (8 heads)
    const int b  = blockIdx.y;
    const int tid = threadIdx.x;

    __shared__ float svk[8][64];
    __shared__ float sginv[8][8];

    for (int i = tid; i < 8 * 64; i += 256) {
        int h = i >> 6;
        svk[h][i & 63] = stats[((size_t)b * 64 + hg * 8 + h) * 72 + (i & 63)];
    }
    if (tid < 64)
        sginv[tid >> 3][tid & 7] =
            1.0f / (stats[((size_t)b * 64 + hg * 8 + (tid >> 3)) * 72 + 64 + (tid & 7)] + EPS_F);
    __syncthreads();

    const float* wr = projw + (size_t)tid * 512 + hg * 64;
    #pragma unroll
    for (int hh = 0; hh < 8; hh++) {
        float wv[8];
        float4 a0 = *reinterpret_cast<const float4*>(wr + hh * 8);
        float4 a1 = *reinterpret_cast<const float4*>(wr + hh * 8 + 4);
        wv[0]=a0.x; wv[1]=a0.y; wv[2]=a0.z; wv[3]=a0.w;
        wv[4]=a1.x; wv[5]=a1.y; wv[6]=a1.z; wv[7]=a1.w;
        union { _Float16 h8[8]; uint4 u; } hi, lo;
        #pragma unroll
        for (int e = 0; e < 8; e++) {
            float s = 0.f;
            #pragma unroll
            for (int d = 0; d < 8; d++) s += wv[d] * svk[hh][d * 8 + e];
            s *= sginv[hh][e];
            _Float16 sh = (_Float16)s;
            hi.h8[e] = sh;
            lo.h8[e] = (_Float16)(s - (float)sh);
        }
        size_t off = ((size_t)b * 256 + tid) * 512 + hg * 64 + hh * 8;
        *reinterpret_cast<uint4*>(Mhi + off) = hi.u;
        *reinterpret_cast<uint4*>(Mlo + off) = lo.u;
    }
}

// ---------------------------------------------------------------------------
// K5: 128-px tile, 4 barriers total. Qt_e = QSCALE*g_e*q_e/den (bounded),
// f16; two half-K phases (heads 0..31 from Qf, 32..63 from Qagg), each a
// 2-pass hi/lo f16 MFMA GEMM (256ch x 128px). LDS ~70 KB -> 2 blocks/CU.
// ---------------------------------------------------------------------------
__global__ __launch_bounds__(256) void attn_proj_mfma(
    const float* __restrict__ Qf,      // (B,256,HW) packed q (>=0)
    const float* __restrict__ Qagg,    // (B,256,HW) packed dwconv(q), raw
    const float* __restrict__ stats,   // ksum at [64..71]
    const _Float16* __restrict__ Mhi,  // (B,256,512)
    const _Float16* __restrict__ Mlo,
    const float* __restrict__ scale, const float* __restrict__ bias,
    float* __restrict__ out)           // (B,256,HW)
{
    const int pt  = blockIdx.x * 128;
    const int b   = blockIdx.y;
    const int tid = threadIdx.x;
    const int wv  = tid >> 6, lane = tid & 63;

    __shared__ _Float16 Qt[128][264];     // 67.6 KB half-K [px][k]
    __shared__ float    ksums[64][8];     // 2 KB

    for (int i = tid; i < 512; i += 256)
        ksums[i >> 3][i & 7] = stats[((size_t)b * 64 + (i >> 3)) * 72 + 64 + (i & 7)];
    __syncthreads();

    const int pxl = tid & 127;            // local pixel for Qt build
    const int eg  = (tid >> 7) * 4;       // 4 e's per thread
    const int u = lane & 15, q8 = (lane >> 4) * 8;
    const int quad = lane >> 4;

    floatx4 acc[4][8];
    #pragma unroll
    for (int i = 0; i < 4; i++)
        #pragma unroll
        for (int j = 0; j < 8; j++) acc[i][j] = (floatx4)0.f;

    // ============ phase A: heads 0..31 (q direct from Qf, >=0) ============
    for (int h = 0; h < 32; h++) {
        const float* qp = Qf + ((size_t)b * 256 + h * 8) * HW + pt + pxl;
        float qv[8];
        #pragma unroll
        for (int e = 0; e < 8; e++) qv[e] = qp[(size_t)e * HW];
        float den = EPS_F;
        #pragma unroll
        for (int e = 0; e < 8; e++) den += ksums[h][e] * qv[e];
        float rd = QSCALE / den;
        union { _Float16 h4[4]; uint2 u2; } pk;
        #pragma unroll
        for (int j = 0; j < 4; j++) {
            float g = ksums[h][eg + j] + EPS_F;
            pk.h4[j] = (_Float16)fminf(qv[eg + j] * g * rd, 60000.f);
        }
        *reinterpret_cast<uint2*>(&Qt[pxl][h * 8 + eg]) = pk.u2;
    }
    __syncthreads();

    for (int ks = 0; ks < 8; ks++) {
        half8 ah[4], al[4], bf[8];
        #pragma unroll
        for (int mt = 0; mt < 4; mt++) {
            size_t moff = ((size_t)b * 256 + wv * 64 + mt * 16 + u) * 512 + ks * 32 + q8;
            ah[mt] = *reinterpret_cast<const half8*>(Mhi + moff);
            al[mt] = *reinterpret_cast<const half8*>(Mlo + moff);
        }
        #pragma unroll
        for (int nt = 0; nt < 8; nt++)
            bf[nt] = *reinterpret_cast<const half8*>(&Qt[nt * 16 + u][ks * 32 + q8]);
        #pragma unroll
        for (int mt = 0; mt < 4; mt++)
            #pragma unroll
            for (int nt = 0; nt < 8; nt++) {
                acc[mt][nt] = __builtin_amdgcn_mfma_f32_16x16x32_f16(ah[mt], bf[nt], acc[mt][nt], 0, 0, 0);
                acc[mt][nt] = __builtin_amdgcn_mfma_f32_16x16x32_f16(al[mt], bf[nt], acc[mt][nt], 0, 0, 0);
            }
    }
    __syncthreads();

    // ============ phase B: heads 32..63 (q from Qagg, needs relu) ==========
    for (int h = 32; h < 64; h++) {
        const int hb = h - 32;
        const float* qp = Qagg + ((size_t)b * 256 + hb * 8) * HW + pt + pxl;
        float qv[8];
        #pragma unroll
        for (int e = 0; e < 8; e++) qv[e] = fmaxf(qp[(size_t)e * HW], 0.f);
        float den = EPS_F;
        #pragma unroll
        for (int e = 0; e < 8; e++) den += ksums[h][e] * qv[e];
        float rd = QSCALE / den;
        union { _Float16 h4[4]; uint2 u2; } pk;
        #pragma unroll
        for (int j = 0; j < 4; j++) {
            float g = ksums[h][eg + j] + EPS_F;
            pk.h4[j] = (_Float16)fminf(qv[eg + j] * g * rd, 60000.f);
        }
        *reinterpret_cast<uint2*>(&Qt[pxl][hb * 8 + eg]) = pk.u2;
    }
    __syncthreads();

    for (int ks = 0; ks < 8; ks++) {
        half8 ah[4], al[4], bf[8];
        #pragma unroll
        for (int mt = 0; mt < 4; mt++) {
            size_t moff = ((size_t)b * 256 + wv * 64 + mt * 16 + u) * 512 + 256 + ks * 32 + q8;
            ah[mt] = *reinterpret_cast<const half8*>(Mhi + moff);
            al[mt] = *reinterpret_cast<const half8*>(Mlo + moff);
        }
        #pragma unroll
        for (int nt = 0; nt < 8; nt++)
            bf[nt] = *reinterpret_cast<const half8*>(&Qt[nt * 16 + u][ks * 32 + q8]);
        #pragma unroll
        for (int mt = 0; mt < 4; mt++)
            #pragma unroll
            for (int nt = 0; nt < 8; nt++) {
                acc[mt][nt] = __builtin_amdgcn_mfma_f32_16x16x32_f16(ah[mt], bf[nt], acc[mt][nt], 0, 0, 0);
                acc[mt][nt] = __builtin_amdgcn_mfma_f32_16x16x32_f16(al[mt], bf[nt], acc[mt][nt], 0, 0, 0);
            }
    }

    #pragma unroll
    for (int mt = 0; mt < 4; mt++)
        #pragma unroll
        for (int r = 0; r < 4; r++) {
            int c = wv * 64 + mt * 16 + quad * 4 + r;
            float s = scale[c] * (1.0f / QSCALE);
            float bi = bias[c];
            #pragma unroll
            for (int nt = 0; nt < 8; nt++) {
                int px = pt + nt * 16 + u;
                out[((size_t)b * COUT + c) * HW + px] = fmaxf(acc[mt][nt][r] * s + bi, 0.f);
            }
        }
}

// ---------------------------------------------------------------------------
extern "C" void kernel_launch(void* const* d_in, const int* in_sizes, int n_in,
                              void* d_out, int out_size, void* d_ws, size_t ws_size,
                              hipStream_t stream)
{
    const float* x      = (const float*)d_in[0];
    const float* qkv_w  = (const float*)d_in[1];
    const float* qkv_s  = (const float*)d_in[2];
    const float* qkv_b  = (const float*)d_in[3];
    const float* dw_w   = (const float*)d_in[4];
    const float* dw_b   = (const float*)d_in[5];
    const float* pw_w   = (const float*)d_in[6];
    const float* pw_b   = (const float*)d_in[7];
    const float* proj_w = (const float*)d_in[8];
    const float* proj_s = (const float*)d_in[9];
    const float* proj_b = (const float*)d_in[10];
    float* out = (float*)d_out;

    // ws layout (exactly the PROVEN 192.3 MiB):
    //   [0,128 MiB)    KV f32 — dead after K2/K3; reused: Mhi(4)+Mlo(4)+Qagg(64)
    //   [128,192 MiB)  Qf f32
    //   [192 MiB,+288K) stats
    float*    KV    = (float*)d_ws;
    _Float16* Mhi   = (_Float16*)d_ws;                          // +0
    _Float16* Mlo   = Mhi + (size_t)BATCH * 256 * 512;          // +4 MiB
    float*    Qagg  = (float*)(Mlo + (size_t)BATCH * 256 * 512);// +8 MiB (64 MiB)
    float*    Qf    = KV + (size_t)BATCH * 512 * HW;            // +128 MiB
    float*    stats = Qf + (size_t)BATCH * 256 * HW;            // +192 MiB

    conv_q_f32<<<dim3(HW / 128, 2, BATCH), 256, 0, stream>>>(
        x, qkv_w, qkv_s, qkv_b, Qf);

    conv_kv_mfma<<<dim3(4, 32, BATCH), 256, 0, stream>>>(
        x, qkv_w, qkv_s, qkv_b, KV);

    // zero stats before the atomic-reduce stats kernels
    zero_stats<<<dim3((BATCH * 64 * 72 + 255) / 256), 256, 0, stream>>>(stats);

    attn_stats_direct<<<dim3(32, 4, BATCH), 256, 0, stream>>>(KV, stats);

    attn_stats_dw<<<dim3(32, 2, BATCH), 256, 0, stream>>>(
        KV, dw_w, dw_b, pw_w, pw_b, stats);

    // after K2/K3: KV region dead -> safe to overwrite with Qagg / M
    q_dwconv<<<dim3(32, 2, BATCH), 256, 0, stream>>>(
        Qf, dw_w, dw_b, pw_w, pw_b, Qagg);

    build_M<<<dim3(8, BATCH), 256, 0, stream>>>(stats, proj_w, Mhi, Mlo);

    attn_proj_mfma<<<dim3(HW / 128, BATCH), 256, 0, stream>>>(
        Qf, Qagg, stats, Mhi, Mlo, proj_s, proj_b, out);
}

// Round 10
// 568.506 us; speedup vs baseline: 1.0607x; 1.0607x over previous
//
#include <hip/hip_runtime.h>

#define HW    4096
#define WIMG  64
#define CIN   256
#define C3    768
#define COUT  256
#define BATCH 16
#define NHB   32
#define EPS_F 1e-5f
#define QSCALE 1024.0f   // pow2: exactly undone in epilogue

typedef __attribute__((ext_vector_type(8))) short    short8;
typedef __attribute__((ext_vector_type(8))) _Float16 half8;
typedef __attribute__((ext_vector_type(4))) float    floatx4;

__device__ inline short f32_to_bf16(float f) {
    unsigned u = __builtin_bit_cast(unsigned, f);
    unsigned r = u + 0x7fffu + ((u >> 16) & 1u);
    return (short)(r >> 16);
}
__device__ inline float bf16_to_f32(short s) {
    return __builtin_bit_cast(float, ((unsigned)(unsigned short)s) << 16);
}

// ---------------------------------------------------------------------------
// K1a v3: q channels (packed 256) of qkv 1x1 conv, f32 VALU GEMM.
// 128x128 tile, 8x8 per thread. q stays f32 (eps-denominator cliff).
// v3 = round-8 structure (direct staging, VGPR ~92, no reg-dbuf: r9 showed
// dbuf pushes VGPR past the 128 occupancy cliff, -50% waves) + Ws row
// stride 132 (staging-write banks (4k+c)%32 cover all banks 2x/wave;
// r9 verified conflicts 1.57e7 -> 1.05e6). Rows stay 16B-aligned (528 B).
// ---------------------------------------------------------------------------
__global__ __launch_bounds__(256) void conv_q_f32(
    const float* __restrict__ in,     // (B, 256, HW)
    const float* __restrict__ w,      // (768, 256)
    const float* __restrict__ scale,
    const float* __restrict__ bias,
    float* __restrict__ Qf)           // (B, 256, HW) packed q
{
    const int pt  = blockIdx.x * 128;
    const int ct  = blockIdx.y * 128;
    const int b   = blockIdx.z;
    const int tid = threadIdx.x;
    const int tx  = tid & 15;         // px groups tx*4 and 64+tx*4
    const int ty  = tid >> 4;         // ch groups ty*4 and 64+ty*4

    __shared__ float Ws[16][132];     // padded: conflict-free staging writes
    __shared__ float Xs[16][128];

    float acc[8][8] = {};
    const float* xb = in + (size_t)b * CIN * HW + pt;

    for (int k0 = 0; k0 < CIN; k0 += 16) {
        #pragma unroll
        for (int i = 0; i < 8; i++) {
            int idx = tid + i * 256;          // 0..2047
            int c = idx >> 4, k = idx & 15;
            int cp = ct + c;
            int creal = (cp >> 3) * 24 + (cp & 7);
            Ws[k][c] = w[(size_t)creal * CIN + k0 + k];
        }
        #pragma unroll
        for (int i = 0; i < 8; i++) {
            int idx = tid + i * 256;
            int k = idx >> 7, p = idx & 127;
            Xs[k][p] = xb[(size_t)(k0 + k) * HW + p];
        }
        __syncthreads();
        #pragma unroll
        for (int kk = 0; kk < 16; kk++) {
            float4 a0 = *reinterpret_cast<const float4*>(&Ws[kk][ty * 4]);
            float4 a1 = *reinterpret_cast<const float4*>(&Ws[kk][64 + ty * 4]);
            float4 b0 = *reinterpret_cast<const float4*>(&Xs[kk][tx * 4]);
            float4 b1 = *reinterpret_cast<const float4*>(&Xs[kk][64 + tx * 4]);
            float a[8] = {a0.x, a0.y, a0.z, a0.w, a1.x, a1.y, a1.z, a1.w};
            float bb[8] = {b0.x, b0.y, b0.z, b0.w, b1.x, b1.y, b1.z, b1.w};
            #pragma unroll
            for (int i = 0; i < 8; i++)
                #pragma unroll
                for (int j = 0; j < 8; j++)
                    acc[i][j] += a[i] * bb[j];
        }
        __syncthreads();
    }

    #pragma unroll
    for (int i = 0; i < 8; i++) {
        int cp = ct + (i < 4 ? ty * 4 + i : 64 + ty * 4 + (i - 4));
        int creal = (cp >> 3) * 24 + (cp & 7);
        float s = scale[creal];
        float bi = bias[creal];
        float4 v0, v1;
        v0.x = fmaxf(acc[i][0] * s + bi, 0.f);
        v0.y = fmaxf(acc[i][1] * s + bi, 0.f);
        v0.z = fmaxf(acc[i][2] * s + bi, 0.f);
        v0.w = fmaxf(acc[i][3] * s + bi, 0.f);
        v1.x = fmaxf(acc[i][4] * s + bi, 0.f);
        v1.y = fmaxf(acc[i][5] * s + bi, 0.f);
        v1.z = fmaxf(acc[i][6] * s + bi, 0.f);
        v1.w = fmaxf(acc[i][7] * s + bi, 0.f);
        float* dst = Qf + ((size_t)b * 256 + cp) * HW + pt;
        *reinterpret_cast<float4*>(dst + tx * 4)      = v0;
        *reinterpret_cast<float4*>(dst + 64 + tx * 4) = v1;
    }
}

// ---------------------------------------------------------------------------
// K1b: k/v channels (packed 512) via bf16 hi/lo 3-pass MFMA (~f32 accurate).
// Packed c' in [0,512): real = (c'>>4)*24 + 8 + (c'&15). Out f32.
// ---------------------------------------------------------------------------
__global__ __launch_bounds__(256) void conv_kv_mfma(
    const float* __restrict__ x,
    const float* __restrict__ w,
    const float* __restrict__ scale,
    const float* __restrict__ bias,
    float* __restrict__ KV)           // (B, 512, HW) packed k/v, f32
{
    const int ct = blockIdx.x, pt = blockIdx.y, b = blockIdx.z;
    const int tid  = threadIdx.x;
    const int wv   = tid >> 6, lane = tid & 63;
    const int u    = lane & 15, q8 = (lane >> 4) * 8;
    const int chb  = ct * 128 + (wv >> 1) * 64;
    const int pxb  = pt * 128 + (wv & 1) * 64;

    floatx4 acc[4][4];
    #pragma unroll
    for (int i = 0; i < 4; i++)
        #pragma unroll
        for (int j = 0; j < 4; j++) acc[i][j] = (floatx4)0.f;

    for (int kc = 0; kc < 8; kc++) {
        const int k0 = kc * 32 + q8;
        short8 ahi[4], alo[4];
        #pragma unroll
        for (int mt = 0; mt < 4; mt++) {
            int cp = chb + mt * 16 + u;
            int creal = (cp >> 4) * 24 + 8 + (cp & 15);
            const float* wp = w + (size_t)creal * CIN + k0;
            #pragma unroll
            for (int j = 0; j < 8; j++) {
                float f = wp[j];
                short h = f32_to_bf16(f);
                ahi[mt][j] = h;
                alo[mt][j] = f32_to_bf16(f - bf16_to_f32(h));
            }
        }
        short8 bhi[4], blo[4];
        #pragma unroll
        for (int nt = 0; nt < 4; nt++) {
            const float* xp = x + ((size_t)b * CIN + k0) * HW + pxb + nt * 16 + u;
            #pragma unroll
            for (int j = 0; j < 8; j++) {
                float f = xp[(size_t)j * HW];
                short h = f32_to_bf16(f);
                bhi[nt][j] = h;
                blo[nt][j] = f32_to_bf16(f - bf16_to_f32(h));
            }
        }
        #pragma unroll
        for (int mt = 0; mt < 4; mt++)
            #pragma unroll
            for (int nt = 0; nt < 4; nt++) {
                acc[mt][nt] = __builtin_amdgcn_mfma_f32_16x16x32_bf16(ahi[mt], bhi[nt], acc[mt][nt], 0, 0, 0);
                acc[mt][nt] = __builtin_amdgcn_mfma_f32_16x16x32_bf16(ahi[mt], blo[nt], acc[mt][nt], 0, 0, 0);
                acc[mt][nt] = __builtin_amdgcn_mfma_f32_16x16x32_bf16(alo[mt], bhi[nt], acc[mt][nt], 0, 0, 0);
            }
    }

    const int quad = lane >> 4;
    #pragma unroll
    for (int mt = 0; mt < 4; mt++)
        #pragma unroll
        for (int r = 0; r < 4; r++) {
            int cp = chb + mt * 16 + quad * 4 + r;
            int creal = (cp >> 4) * 24 + 8 + (cp & 15);
            float s = scale[creal], bi = bias[creal];
            #pragma unroll
            for (int nt = 0; nt < 4; nt++) {
                int px = pxb + nt * 16 + u;
                KV[((size_t)b * 512 + cp) * HW + px] = fmaxf(acc[mt][nt][r] * s + bi, 0.f);
            }
        }
}

// ---------------------------------------------------------------------------
// K0z: zero the stats region (atomic consumers below; re-entrant per launch).
// ---------------------------------------------------------------------------
__global__ __launch_bounds__(256) void zero_stats(float* __restrict__ stats)
{
    int i = blockIdx.x * 256 + threadIdx.x;
    if (i < BATCH * 64 * 72) stats[i] = 0.f;
}

// ---------------------------------------------------------------------------
// K2 v6: stats heads 0..31 via MFMA GRAM. Lane (c=lane&15, kg=lane>>4)
// streams 8 px of channel c per 32-px step; same short8 is both A-row c and
// B-col c of mfma_f32_16x16x32_bf16 -> D = Gram (16x16); rows 8..15 x cols
// 0..7 = vk. ksum via B=ones MFMA. bf16 hi/lo 3-pass ~f32. No LDS/barriers.
// grid (32 h, 4 ps, 16 b) = 2048 blocks.
// ---------------------------------------------------------------------------
__global__ __launch_bounds__(256) void attn_stats_direct(
    const float* __restrict__ KV,
    float* __restrict__ stats)
{
    const int h = blockIdx.x, ps = blockIdx.y, b = blockIdx.z;
    const int tid = threadIdx.x;
    const int lane = tid & 63, wv = tid >> 6;
    const int c  = lane & 15;
    const int kg = lane >> 4;

    const float* cb = KV + ((size_t)b * 512 + h * 16 + c) * HW
                    + ps * 1024 + wv * 256 + kg * 8;

    floatx4 accg = (floatx4)0.f;     // gram
    floatx4 accs = (floatx4)0.f;     // rowsums (ksum in rows 0..7)
    short8 ones;
    #pragma unroll
    for (int j = 0; j < 8; j++) ones[j] = (short)0x3F80;  // bf16 1.0

    for (int st = 0; st < 8; st++) {
        float4 f0 = *reinterpret_cast<const float4*>(cb + st * 32);
        float4 f1 = *reinterpret_cast<const float4*>(cb + st * 32 + 4);
        float v[8] = {f0.x, f0.y, f0.z, f0.w, f1.x, f1.y, f1.z, f1.w};
        short8 hi, lo;
        #pragma unroll
        for (int j = 0; j < 8; j++) {
            short hh = f32_to_bf16(v[j]);
            hi[j] = hh;
            lo[j] = f32_to_bf16(v[j] - bf16_to_f32(hh));
        }
        accg = __builtin_amdgcn_mfma_f32_16x16x32_bf16(hi, hi, accg, 0, 0, 0);
        accg = __builtin_amdgcn_mfma_f32_16x16x32_bf16(hi, lo, accg, 0, 0, 0);
        accg = __builtin_amdgcn_mfma_f32_16x16x32_bf16(lo, hi, accg, 0, 0, 0);
        accs = __builtin_amdgcn_mfma_f32_16x16x32_bf16(hi, ones, accs, 0, 0, 0);
        accs = __builtin_amdgcn_mfma_f32_16x16x32_bf16(lo, ones, accs, 0, 0, 0);
    }

    // D layout: col = lane&15, row = (lane>>4)*4 + r
    float* sb = stats + ((size_t)b * 64 + h) * 72;
    if (c < 8 && kg >= 2) {           // rows 8..15 (v), cols 0..7 (k)
        #pragma unroll
        for (int r = 0; r < 4; r++)
            atomicAdd(sb + ((kg - 2) * 4 + r) * 8 + c, accg[r]);
    }
    if (c == 0 && kg < 2) {           // ksum rows 0..7, any col -> col 0
        #pragma unroll
        for (int r = 0; r < 4; r++)
            atomicAdd(sb + 64 + kg * 4 + r, accs[r]);
    }
}

// ---------------------------------------------------------------------------
// K3 v7: stats heads 32..63 = rolling-window 5x5 dwconv fused with MFMA GRAM.
// Each input row is loaded ONCE (12 rows/strip) and scattered into the <=5
// live output-row accumulators out[5][8] (rotating slots, full unroll ->
// compile-time indices). When input li lands, output li-4 completes ->
// affine -> relu(k) -> bf16 hi/lo -> 5 Gram/ksum MFMAs -> slot reset.
// No LDS, no barriers. grid (32 hp, 2 ysb, 16 b) = 1024 blocks.
// ---------------------------------------------------------------------------
__global__ __launch_bounds__(256) void attn_stats_dw(
    const float* __restrict__ KV,
    const float* __restrict__ dww, const float* __restrict__ dwb,
    const float* __restrict__ pww, const float* __restrict__ pwb,
    float* __restrict__ stats)
{
    const int hp = blockIdx.x, ysb = blockIdx.y, b = blockIdx.z;
    const int tid = threadIdx.x;
    const int lane = tid & 63, wv = tid >> 6;
    const int c  = lane & 15;
    const int kg = lane >> 4;
    const int creal = hp * 24 + 8 + c;

    float wt[25];
    #pragma unroll
    for (int i = 0; i < 25; i++) wt[i] = dww[creal * 25 + i];
    const float pw = pww[creal];
    const float pb = pw * dwb[creal] + pwb[creal];

    const float* cb = KV + ((size_t)b * 512 + hp * 16 + c) * HW;
    const int ybase = ysb * 32 + wv * 8;

    floatx4 accg = (floatx4)0.f;
    floatx4 accs = (floatx4)0.f;
    short8 ones;
    #pragma unroll
    for (int j = 0; j < 8; j++) ones[j] = (short)0x3F80;

    #pragma unroll
    for (int xh = 0; xh < 2; xh++) {
        const int x0 = xh * 32 + kg * 8;
        const float mL = (x0 == 0)  ? 0.f : 1.f;
        const float mR = (x0 == 56) ? 0.f : 1.f;
        const int colL = (x0 == 0)  ? 0  : x0 - 4;
        const int colR = (x0 == 56) ? 56 : x0 + 8;

        float out[5][8] = {};
        #pragma unroll
        for (int li = 0; li < 12; li++) {
            const int ry = ybase + li - 2;
            float4 Q0 = {0,0,0,0}, Q1 = {0,0,0,0}, Q2 = {0,0,0,0}, Q3 = {0,0,0,0};
            if (ry >= 0 && ry < WIMG) {          // wave-uniform
                const float* rp = cb + ry * WIMG;
                Q0 = *reinterpret_cast<const float4*>(rp + colL);
                Q1 = *reinterpret_cast<const float4*>(rp + x0);
                Q2 = *reinterpret_cast<const float4*>(rp + x0 + 4);
                Q3 = *reinterpret_cast<const float4*>(rp + colR);
            }
            float win[12] = {Q0.z * mL, Q0.w * mL,
                             Q1.x, Q1.y, Q1.z, Q1.w,
                             Q2.x, Q2.y, Q2.z, Q2.w,
                             Q3.x * mR, Q3.y * mR};
            // scatter into live output rows lo = li-4..li
            #pragma unroll
            for (int rr = 0; rr < 5; rr++) {
                const int lo = li - rr;
                if (lo >= 0 && lo < 8) {
                    #pragma unroll
                    for (int kx = 0; kx < 5; kx++) {
                        float w5 = wt[rr * 5 + kx];
                        #pragma unroll
                        for (int j = 0; j < 8; j++)
                            out[lo % 5][j] += w5 * win[j + kx];
                    }
                }
            }
            // finalize completed output row lo = li-4
            const int lod = li - 4;
            if (lod >= 0 && lod < 8) {
                short8 hib, lob;
                #pragma unroll
                for (int j = 0; j < 8; j++) {
                    float v = out[lod % 5][j] * pw + pb;
                    float vr = fmaxf(v, 0.f);
                    v = (c < 8) ? vr : v;        // relu k-channels only
                    short hh = f32_to_bf16(v);
                    hib[j] = hh;
                    lob[j] = f32_to_bf16(v - bf16_to_f32(hh));
                }
                accg = __builtin_amdgcn_mfma_f32_16x16x32_bf16(hib, hib, accg, 0, 0, 0);
                accg = __builtin_amdgcn_mfma_f32_16x16x32_bf16(hib, lob, accg, 0, 0, 0);
                accg = __builtin_amdgcn_mfma_f32_16x16x32_bf16(lob, hib, accg, 0, 0, 0);
                accs = __builtin_amdgcn_mfma_f32_16x16x32_bf16(hib, ones, accs, 0, 0, 0);
                accs = __builtin_amdgcn_mfma_f32_16x16x32_bf16(lob, ones, accs, 0, 0, 0);
                #pragma unroll
                for (int j = 0; j < 8; j++) out[lod % 5][j] = 0.f;
            }
        }
    }

    float* sb = stats + ((size_t)b * 64 + 32 + hp) * 72;
    if (c < 8 && kg >= 2) {
        #pragma unroll
        for (int r = 0; r < 4; r++)
            atomicAdd(sb + ((kg - 2) * 4 + r) * 8 + c, accg[r]);
    }
    if (c == 0 && kg < 2) {
        #pragma unroll
        for (int r = 0; r < 4; r++)
            atomicAdd(sb + 64 + kg * 4 + r, accs[r]);
    }
}

// ---------------------------------------------------------------------------
// K3b v7: Qagg = rolling-window 5x5 dwconv + affine of q channels; each input
// row loaded once, out[5][8] rotating slots, finalize -> 2x float4 store.
// Lane (c=lane&7, g=lane>>3) covers 8 px of channel c; wave = full 64-px row
// x 8 channels. grid (32 hb, 2 ysb, 16 b) = 1024 blocks. Raw out (relu K5).
// ---------------------------------------------------------------------------
__global__ __launch_bounds__(256) void q_dwconv(
    const float* __restrict__ Qf,     // (B,256,HW) packed q
    const float* __restrict__ dww, const float* __restrict__ dwb,
    const float* __restrict__ pww, const float* __restrict__ pwb,
    float* __restrict__ Qagg)         // (B,256,HW) packed dwconv(q)
{
    const int hb = blockIdx.x, ysb = blockIdx.y, b = blockIdx.z;
    const int tid = threadIdx.x;
    const int lane = tid & 63, wv = tid >> 6;
    const int c = lane & 7;
    const int g = lane >> 3;          // 0..7
    const int x0 = g * 8;
    const int creal = hb * 24 + c;

    float wt[25];
    #pragma unroll
    for (int i = 0; i < 25; i++) wt[i] = dww[creal * 25 + i];
    const float pw = pww[creal];
    const float pb = pw * dwb[creal] + pwb[creal];

    const float mL = (x0 == 0)  ? 0.f : 1.f;
    const float mR = (x0 == 56) ? 0.f : 1.f;
    const int colL = (x0 == 0)  ? 0  : x0 - 4;
    const int colR = (x0 == 56) ? 56 : x0 + 8;

    const float* cbase = Qf   + ((size_t)b * 256 + hb * 8 + c) * HW;
    float*       obase = Qagg + ((size_t)b * 256 + hb * 8 + c) * HW;
    const int ybase = ysb * 32 + wv * 8;

    float out[5][8] = {};
    #pragma unroll
    for (int li = 0; li < 12; li++) {
        const int ry = ybase + li - 2;
        float4 Q0 = {0,0,0,0}, Q1 = {0,0,0,0}, Q2 = {0,0,0,0}, Q3 = {0,0,0,0};
        if (ry >= 0 && ry < WIMG) {
            const float* rp = cbase + ry * WIMG;
            Q0 = *reinterpret_cast<const float4*>(rp + colL);
            Q1 = *reinterpret_cast<const float4*>(rp + x0);
            Q2 = *reinterpret_cast<const float4*>(rp + x0 + 4);
            Q3 = *reinterpret_cast<const float4*>(rp + colR);
        }
        float win[12] = {Q0.z * mL, Q0.w * mL,
                         Q1.x, Q1.y, Q1.z, Q1.w,
                         Q2.x, Q2.y, Q2.z, Q2.w,
                         Q3.x * mR, Q3.y * mR};
        #pragma unroll
        for (int rr = 0; rr < 5; rr++) {
            const int lo = li - rr;
            if (lo >= 0 && lo < 8) {
                #pragma unroll
                for (int kx = 0; kx < 5; kx++) {
                    float w5 = wt[rr * 5 + kx];
                    #pragma unroll
                    for (int j = 0; j < 8; j++)
                        out[lo % 5][j] += w5 * win[j + kx];
                }
            }
        }
        const int lod = li - 4;
        if (lod >= 0 && lod < 8) {
            float4 o0 = {out[lod % 5][0] * pw + pb, out[lod % 5][1] * pw + pb,
                         out[lod % 5][2] * pw + pb, out[lod % 5][3] * pw + pb};
            float4 o1 = {out[lod % 5][4] * pw + pb, out[lod % 5][5] * pw + pb,
                         out[lod % 5][6] * pw + pb, out[lod % 5][7] * pw + pb};
            float* dst = obase + (ybase + lod) * WIMG + x0;
            *reinterpret_cast<float4*>(dst)     = o0;
            *reinterpret_cast<float4*>(dst + 4) = o1;
            #pragma unroll
            for (int j = 0; j < 8; j++) out[lod % 5][j] = 0.f;
        }
    }
}

// ---------------------------------------------------------------------------
// K4 v2: fold proj weights with vk, COLUMN-RESCALED by g_e = ksum_e + eps.
// Parallelized over head-groups: grid (8 hg, 16 b) = 128 blocks.
// ---------------------------------------------------------------------------
__global__ __launch_bounds__(256) void build_M(
    const float* __restrict__ stats,   // (B,64,72)
    const float* __restrict__ projw,   // (256,512)
    _Float16* __restrict__ Mhi,        // (B,256,512)
    _Float16* __restrict__ Mlo)
{
    const int hg = blockIdx.x;         // head group (8 heads)
    const int b  = blockIdx.y;
    const int tid = threadIdx.x;

    __shared__ float svk[8][64];
    __shared__ float sginv[8][8];

    for (int i = tid; i < 8 * 64; i += 256) {
        int h = i >> 6;
        svk[h][i & 63] = stats[((size_t)b * 64 + hg * 8 + h) * 72 + (i & 63)];
    }
    if (tid < 64)
        sginv[tid >> 3][tid & 7] =
            1.0f / (stats[((size_t)b * 64 + hg * 8 + (tid >> 3)) * 72 + 64 + (tid & 7)] + EPS_F);
    __syncthreads();

    const float* wr = projw + (size_t)tid * 512 + hg * 64;
    #pragma unroll
    for (int hh = 0; hh < 8; hh++) {
        float wv[8];
        float4 a0 = *reinterpret_cast<const float4*>(wr + hh * 8);
        float4 a1 = *reinterpret_cast<const float4*>(wr + hh * 8 + 4);
        wv[0]=a0.x; wv[1]=a0.y; wv[2]=a0.z; wv[3]=a0.w;
        wv[4]=a1.x; wv[5]=a1.y; wv[6]=a1.z; wv[7]=a1.w;
        union { _Float16 h8[8]; uint4 u; } hi, lo;
        #pragma unroll
        for (int e = 0; e < 8; e++) {
            float s = 0.f;
            #pragma unroll
            for (int d = 0; d < 8; d++) s += wv[d] * svk[hh][d * 8 + e];
            s *= sginv[hh][e];
            _Float16 sh = (_Float16)s;
            hi.h8[e] = sh;
            lo.h8[e] = (_Float16)(s - (float)sh);
        }
        size_t off = ((size_t)b * 256 + tid) * 512 + hg * 64 + hh * 8;
        *reinterpret_cast<uint4*>(Mhi + off) = hi.u;
        *reinterpret_cast<uint4*>(Mlo + off) = lo.u;
    }
}

// ---------------------------------------------------------------------------
// K5: 128-px tile, 4 barriers total. Qt_e = QSCALE*g_e*q_e/den (bounded),
// f16; two half-K phases (heads 0..31 from Qf, 32..63 from Qagg), each a
// 2-pass hi/lo f16 MFMA GEMM (256ch x 128px). LDS ~70 KB -> 2 blocks/CU.
// ---------------------------------------------------------------------------
__global__ __launch_bounds__(256) void attn_proj_mfma(
    const float* __restrict__ Qf,      // (B,256,HW) packed q (>=0)
    const float* __restrict__ Qagg,    // (B,256,HW) packed dwconv(q), raw
    const float* __restrict__ stats,   // ksum at [64..71]
    const _Float16* __restrict__ Mhi,  // (B,256,512)
    const _Float16* __restrict__ Mlo,
    const float* __restrict__ scale, const float* __restrict__ bias,
    float* __restrict__ out)           // (B,256,HW)
{
    const int pt  = blockIdx.x * 128;
    const int b   = blockIdx.y;
    const int tid = threadIdx.x;
    const int wv  = tid >> 6, lane = tid & 63;

    __shared__ _Float16 Qt[128][264];     // 67.6 KB half-K [px][k]
    __shared__ float    ksums[64][8];     // 2 KB

    for (int i = tid; i < 512; i += 256)
        ksums[i >> 3][i & 7] = stats[((size_t)b * 64 + (i >> 3)) * 72 + 64 + (i & 7)];
    __syncthreads();

    const int pxl = tid & 127;            // local pixel for Qt build
    const int eg  = (tid >> 7) * 4;       // 4 e's per thread
    const int u = lane & 15, q8 = (lane >> 4) * 8;
    const int quad = lane >> 4;

    floatx4 acc[4][8];
    #pragma unroll
    for (int i = 0; i < 4; i++)
        #pragma unroll
        for (int j = 0; j < 8; j++) acc[i][j] = (floatx4)0.f;

    // ============ phase A: heads 0..31 (q direct from Qf, >=0) ============
    for (int h = 0; h < 32; h++) {
        const float* qp = Qf + ((size_t)b * 256 + h * 8) * HW + pt + pxl;
        float qv[8];
        #pragma unroll
        for (int e = 0; e < 8; e++) qv[e] = qp[(size_t)e * HW];
        float den = EPS_F;
        #pragma unroll
        for (int e = 0; e < 8; e++) den += ksums[h][e] * qv[e];
        float rd = QSCALE / den;
        union { _Float16 h4[4]; uint2 u2; } pk;
        #pragma unroll
        for (int j = 0; j < 4; j++) {
            float g = ksums[h][eg + j] + EPS_F;
            pk.h4[j] = (_Float16)fminf(qv[eg + j] * g * rd, 60000.f);
        }
        *reinterpret_cast<uint2*>(&Qt[pxl][h * 8 + eg]) = pk.u2;
    }
    __syncthreads();

    for (int ks = 0; ks < 8; ks++) {
        half8 ah[4], al[4], bf[8];
        #pragma unroll
        for (int mt = 0; mt < 4; mt++) {
            size_t moff = ((size_t)b * 256 + wv * 64 + mt * 16 + u) * 512 + ks * 32 + q8;
            ah[mt] = *reinterpret_cast<const half8*>(Mhi + moff);
            al[mt] = *reinterpret_cast<const half8*>(Mlo + moff);
        }
        #pragma unroll
        for (int nt = 0; nt < 8; nt++)
            bf[nt] = *reinterpret_cast<const half8*>(&Qt[nt * 16 + u][ks * 32 + q8]);
        #pragma unroll
        for (int mt = 0; mt < 4; mt++)
            #pragma unroll
            for (int nt = 0; nt < 8; nt++) {
                acc[mt][nt] = __builtin_amdgcn_mfma_f32_16x16x32_f16(ah[mt], bf[nt], acc[mt][nt], 0, 0, 0);
                acc[mt][nt] = __builtin_amdgcn_mfma_f32_16x16x32_f16(al[mt], bf[nt], acc[mt][nt], 0, 0, 0);
            }
    }
    __syncthreads();

    // ============ phase B: heads 32..63 (q from Qagg, needs relu) ==========
    for (int h = 32; h < 64; h++) {
        const int hb = h - 32;
        const float* qp = Qagg + ((size_t)b * 256 + hb * 8) * HW + pt + pxl;
        float qv[8];
        #pragma unroll
        for (int e = 0; e < 8; e++) qv[e] = fmaxf(qp[(size_t)e * HW], 0.f);
        float den = EPS_F;
        #pragma unroll
        for (int e = 0; e < 8; e++) den += ksums[h][e] * qv[e];
        float rd = QSCALE / den;
        union { _Float16 h4[4]; uint2 u2; } pk;
        #pragma unroll
        for (int j = 0; j < 4; j++) {
            float g = ksums[h][eg + j] + EPS_F;
            pk.h4[j] = (_Float16)fminf(qv[eg + j] * g * rd, 60000.f);
        }
        *reinterpret_cast<uint2*>(&Qt[pxl][hb * 8 + eg]) = pk.u2;
    }
    __syncthreads();

    for (int ks = 0; ks < 8; ks++) {
        half8 ah[4], al[4], bf[8];
        #pragma unroll
        for (int mt = 0; mt < 4; mt++) {
            size_t moff = ((size_t)b * 256 + wv * 64 + mt * 16 + u) * 512 + 256 + ks * 32 + q8;
            ah[mt] = *reinterpret_cast<const half8*>(Mhi + moff);
            al[mt] = *reinterpret_cast<const half8*>(Mlo + moff);
        }
        #pragma unroll
        for (int nt = 0; nt < 8; nt++)
            bf[nt] = *reinterpret_cast<const half8*>(&Qt[nt * 16 + u][ks * 32 + q8]);
        #pragma unroll
        for (int mt = 0; mt < 4; mt++)
            #pragma unroll
            for (int nt = 0; nt < 8; nt++) {
                acc[mt][nt] = __builtin_amdgcn_mfma_f32_16x16x32_f16(ah[mt], bf[nt], acc[mt][nt], 0, 0, 0);
                acc[mt][nt] = __builtin_amdgcn_mfma_f32_16x16x32_f16(al[mt], bf[nt], acc[mt][nt], 0, 0, 0);
            }
    }

    #pragma unroll
    for (int mt = 0; mt < 4; mt++)
        #pragma unroll
        for (int r = 0; r < 4; r++) {
            int c = wv * 64 + mt * 16 + quad * 4 + r;
            float s = scale[c] * (1.0f / QSCALE);
            float bi = bias[c];
            #pragma unroll
            for (int nt = 0; nt < 8; nt++) {
                int px = pt + nt * 16 + u;
                out[((size_t)b * COUT + c) * HW + px] = fmaxf(acc[mt][nt][r] * s + bi, 0.f);
            }
        }
}

// ---------------------------------------------------------------------------
extern "C" void kernel_launch(void* const* d_in, const int* in_sizes, int n_in,
                              void* d_out, int out_size, void* d_ws, size_t ws_size,
                              hipStream_t stream)
{
    const float* x      = (const float*)d_in[0];
    const float* qkv_w  = (const float*)d_in[1];
    const float* qkv_s  = (const float*)d_in[2];
    const float* qkv_b  = (const float*)d_in[3];
    const float* dw_w   = (const float*)d_in[4];
    const float* dw_b   = (const float*)d_in[5];
    const float* pw_w   = (const float*)d_in[6];
    const float* pw_b   = (const float*)d_in[7];
    const float* proj_w = (const float*)d_in[8];
    const float* proj_s = (const float*)d_in[9];
    const float* proj_b = (const float*)d_in[10];
    float* out = (float*)d_out;

    // ws layout (exactly the PROVEN 192.3 MiB):
    //   [0,128 MiB)    KV f32 — dead after K2/K3; reused: Mhi(4)+Mlo(4)+Qagg(64)
    //   [128,192 MiB)  Qf f32
    //   [192 MiB,+288K) stats
    float*    KV    = (float*)d_ws;
    _Float16* Mhi   = (_Float16*)d_ws;                          // +0
    _Float16* Mlo   = Mhi + (size_t)BATCH * 256 * 512;          // +4 MiB
    float*    Qagg  = (float*)(Mlo + (size_t)BATCH * 256 * 512);// +8 MiB (64 MiB)
    float*    Qf    = KV + (size_t)BATCH * 512 * HW;            // +128 MiB
    float*    stats = Qf + (size_t)BATCH * 256 * HW;            // +192 MiB

    conv_q_f32<<<dim3(HW / 128, 2, BATCH), 256, 0, stream>>>(
        x, qkv_w, qkv_s, qkv_b, Qf);

    conv_kv_mfma<<<dim3(4, 32, BATCH), 256, 0, stream>>>(
        x, qkv_w, qkv_s, qkv_b, KV);

    // zero stats before the atomic-reduce stats kernels
    zero_stats<<<dim3((BATCH * 64 * 72 + 255) / 256), 256, 0, stream>>>(stats);

    attn_stats_direct<<<dim3(32, 4, BATCH), 256, 0, stream>>>(KV, stats);

    attn_stats_dw<<<dim3(32, 2, BATCH), 256, 0, stream>>>(
        KV, dw_w, dw_b, pw_w, pw_b, stats);

    // after K2/K3: KV region dead -> safe to overwrite with Qagg / M
    q_dwconv<<<dim3(32, 2, BATCH), 256, 0, stream>>>(
        Qf, dw_w, dw_b, pw_w, pw_b, Qagg);

    build_M<<<dim3(8, BATCH), 256, 0, stream>>>(stats, proj_w, Mhi, Mlo);

    attn_proj_mfma<<<dim3(HW / 128, BATCH), 256, 0, stream>>>(
        Qf, Qagg, stats, Mhi, Mlo, proj_s, proj_b, out);
}

// Round 11
// 560.437 us; speedup vs baseline: 1.0759x; 1.0144x over previous
//
#include <hip/hip_runtime.h>

#define HW    4096
#define WIMG  64
#define CIN   256
#define C3    768
#define COUT  256
#define BATCH 16
#define NHB   32
#define EPS_F 1e-5f
#define QSCALE 1024.0f   // pow2: exactly undone in epilogue

typedef __attribute__((ext_vector_type(8))) short    short8;
typedef __attribute__((ext_vector_type(8))) _Float16 half8;
typedef __attribute__((ext_vector_type(4))) float    floatx4;

__device__ inline short f32_to_bf16(float f) {
    unsigned u = __builtin_bit_cast(unsigned, f);
    unsigned r = u + 0x7fffu + ((u >> 16) & 1u);
    return (short)(r >> 16);
}
__device__ inline float bf16_to_f32(short s) {
    return __builtin_bit_cast(float, ((unsigned)(unsigned short)s) << 16);
}

// async global->LDS, 4B per lane. lds dest must be wave-uniform base.
__device__ __forceinline__ void async_copy_f32(const float* g, float* l) {
    __builtin_amdgcn_global_load_lds(
        (const __attribute__((address_space(1))) void*)g,
        (__attribute__((address_space(3))) void*)l, 4, 0, 0);
}

// ---------------------------------------------------------------------------
// K1a v4: q channels (packed 256) of qkv 1x1 conv, f32 VALU GEMM.
// 128x128 tile, 8x8 per thread. q stays f32 (eps-denominator cliff).
// v4 = v3 (direct staging, Ws[16][132] padding) with VECTORIZED staging:
//   - Xs via global_load_lds width=4: 8 async instrs/wave, no VGPR roundtrip
//   - Ws via float4-along-k loads (2/thread/iter, was 8 scalar) + 4 scalar
//     ds_writes each; write banks (16kq+4j+c)%32 = exact 2-way/wave = free.
// r9 lesson: NO register prefetch (VGPR 128 cliff). VGPR stays ~90.
// ---------------------------------------------------------------------------
__global__ __launch_bounds__(256) void conv_q_f32(
    const float* __restrict__ in,     // (B, 256, HW)
    const float* __restrict__ w,      // (768, 256)
    const float* __restrict__ scale,
    const float* __restrict__ bias,
    float* __restrict__ Qf)           // (B, 256, HW) packed q
{
    const int pt  = blockIdx.x * 128;
    const int ct  = blockIdx.y * 128;
    const int b   = blockIdx.z;
    const int tid = threadIdx.x;
    const int lane = tid & 63, wv4 = tid >> 6;
    const int tx  = tid & 15;         // px groups tx*4 and 64+tx*4
    const int ty  = tid >> 4;         // ch groups ty*4 and 64+ty*4

    __shared__ float Ws[16][132];     // padded: conflict-free staging writes
    __shared__ float Xs[16][128];

    float acc[8][8] = {};
    const float* xb = in + (size_t)b * CIN * HW + pt;

    // Ws load mapping (k0-invariant): elem in {tid, tid+256};
    // c = elem>>2, kq = elem&3; float4 covers k = kq*4..kq*4+3.
    const int c0 = tid >> 2,        kq0 = tid & 3;
    const int c1 = (tid + 256) >> 2;                 // kq1 == kq0
    const int cp0 = ct + c0, cp1 = ct + c1;
    const int creal0 = (cp0 >> 3) * 24 + (cp0 & 7);
    const int creal1 = (cp1 >> 3) * 24 + (cp1 & 7);
    const float* wp0 = w + (size_t)creal0 * CIN + kq0 * 4;
    const float* wp1 = w + (size_t)creal1 * CIN + kq0 * 4;

    for (int k0 = 0; k0 < CIN; k0 += 16) {
        // ---- stage Ws: 2 float4 global loads + 8 scalar LDS writes ----
        float4 wa = *reinterpret_cast<const float4*>(wp0 + k0);
        float4 wb = *reinterpret_cast<const float4*>(wp1 + k0);
        Ws[kq0 * 4 + 0][c0] = wa.x; Ws[kq0 * 4 + 1][c0] = wa.y;
        Ws[kq0 * 4 + 2][c0] = wa.z; Ws[kq0 * 4 + 3][c0] = wa.w;
        Ws[kq0 * 4 + 0][c1] = wb.x; Ws[kq0 * 4 + 1][c1] = wb.y;
        Ws[kq0 * 4 + 2][c1] = wb.z; Ws[kq0 * 4 + 3][c1] = wb.w;
        // ---- stage Xs: async global->LDS, wave wv4 rows 4*wv4..4*wv4+3 ----
        #pragma unroll
        for (int r = 0; r < 8; r++) {
            int row  = wv4 * 4 + (r >> 1);
            int half = (r & 1) * 64;
            async_copy_f32(xb + (size_t)(k0 + row) * HW + half + lane,
                           &Xs[row][half]);
        }
        __syncthreads();              // drains vmcnt+lgkmcnt (compiler)

        #pragma unroll
        for (int kk = 0; kk < 16; kk++) {
            float4 a0 = *reinterpret_cast<const float4*>(&Ws[kk][ty * 4]);
            float4 a1 = *reinterpret_cast<const float4*>(&Ws[kk][64 + ty * 4]);
            float4 b0 = *reinterpret_cast<const float4*>(&Xs[kk][tx * 4]);
            float4 b1 = *reinterpret_cast<const float4*>(&Xs[kk][64 + tx * 4]);
            float a[8] = {a0.x, a0.y, a0.z, a0.w, a1.x, a1.y, a1.z, a1.w};
            float bb[8] = {b0.x, b0.y, b0.z, b0.w, b1.x, b1.y, b1.z, b1.w};
            #pragma unroll
            for (int i = 0; i < 8; i++)
                #pragma unroll
                for (int j = 0; j < 8; j++)
                    acc[i][j] += a[i] * bb[j];
        }
        __syncthreads();
    }

    #pragma unroll
    for (int i = 0; i < 8; i++) {
        int cp = ct + (i < 4 ? ty * 4 + i : 64 + ty * 4 + (i - 4));
        int creal = (cp >> 3) * 24 + (cp & 7);
        float s = scale[creal];
        float bi = bias[creal];
        float4 v0, v1;
        v0.x = fmaxf(acc[i][0] * s + bi, 0.f);
        v0.y = fmaxf(acc[i][1] * s + bi, 0.f);
        v0.z = fmaxf(acc[i][2] * s + bi, 0.f);
        v0.w = fmaxf(acc[i][3] * s + bi, 0.f);
        v1.x = fmaxf(acc[i][4] * s + bi, 0.f);
        v1.y = fmaxf(acc[i][5] * s + bi, 0.f);
        v1.z = fmaxf(acc[i][6] * s + bi, 0.f);
        v1.w = fmaxf(acc[i][7] * s + bi, 0.f);
        float* dst = Qf + ((size_t)b * 256 + cp) * HW + pt;
        *reinterpret_cast<float4*>(dst + tx * 4)      = v0;
        *reinterpret_cast<float4*>(dst + 64 + tx * 4) = v1;
    }
}

// ---------------------------------------------------------------------------
// K1b: k/v channels (packed 512) via bf16 hi/lo 3-pass MFMA (~f32 accurate).
// Packed c' in [0,512): real = (c'>>4)*24 + 8 + (c'&15). Out f32.
// ---------------------------------------------------------------------------
__global__ __launch_bounds__(256) void conv_kv_mfma(
    const float* __restrict__ x,
    const float* __restrict__ w,
    const float* __restrict__ scale,
    const float* __restrict__ bias,
    float* __restrict__ KV)           // (B, 512, HW) packed k/v, f32
{
    const int ct = blockIdx.x, pt = blockIdx.y, b = blockIdx.z;
    const int tid  = threadIdx.x;
    const int wv   = tid >> 6, lane = tid & 63;
    const int u    = lane & 15, q8 = (lane >> 4) * 8;
    const int chb  = ct * 128 + (wv >> 1) * 64;
    const int pxb  = pt * 128 + (wv & 1) * 64;

    floatx4 acc[4][4];
    #pragma unroll
    for (int i = 0; i < 4; i++)
        #pragma unroll
        for (int j = 0; j < 4; j++) acc[i][j] = (floatx4)0.f;

    for (int kc = 0; kc < 8; kc++) {
        const int k0 = kc * 32 + q8;
        short8 ahi[4], alo[4];
        #pragma unroll
        for (int mt = 0; mt < 4; mt++) {
            int cp = chb + mt * 16 + u;
            int creal = (cp >> 4) * 24 + 8 + (cp & 15);
            const float* wp = w + (size_t)creal * CIN + k0;
            #pragma unroll
            for (int j = 0; j < 8; j++) {
                float f = wp[j];
                short h = f32_to_bf16(f);
                ahi[mt][j] = h;
                alo[mt][j] = f32_to_bf16(f - bf16_to_f32(h));
            }
        }
        short8 bhi[4], blo[4];
        #pragma unroll
        for (int nt = 0; nt < 4; nt++) {
            const float* xp = x + ((size_t)b * CIN + k0) * HW + pxb + nt * 16 + u;
            #pragma unroll
            for (int j = 0; j < 8; j++) {
                float f = xp[(size_t)j * HW];
                short h = f32_to_bf16(f);
                bhi[nt][j] = h;
                blo[nt][j] = f32_to_bf16(f - bf16_to_f32(h));
            }
        }
        #pragma unroll
        for (int mt = 0; mt < 4; mt++)
            #pragma unroll
            for (int nt = 0; nt < 4; nt++) {
                acc[mt][nt] = __builtin_amdgcn_mfma_f32_16x16x32_bf16(ahi[mt], bhi[nt], acc[mt][nt], 0, 0, 0);
                acc[mt][nt] = __builtin_amdgcn_mfma_f32_16x16x32_bf16(ahi[mt], blo[nt], acc[mt][nt], 0, 0, 0);
                acc[mt][nt] = __builtin_amdgcn_mfma_f32_16x16x32_bf16(alo[mt], bhi[nt], acc[mt][nt], 0, 0, 0);
            }
    }

    const int quad = lane >> 4;
    #pragma unroll
    for (int mt = 0; mt < 4; mt++)
        #pragma unroll
        for (int r = 0; r < 4; r++) {
            int cp = chb + mt * 16 + quad * 4 + r;
            int creal = (cp >> 4) * 24 + 8 + (cp & 15);
            float s = scale[creal], bi = bias[creal];
            #pragma unroll
            for (int nt = 0; nt < 4; nt++) {
                int px = pxb + nt * 16 + u;
                KV[((size_t)b * 512 + cp) * HW + px] = fmaxf(acc[mt][nt][r] * s + bi, 0.f);
            }
        }
}

// ---------------------------------------------------------------------------
// K0z: zero the stats region (atomic consumers below; re-entrant per launch).
// ---------------------------------------------------------------------------
__global__ __launch_bounds__(256) void zero_stats(float* __restrict__ stats)
{
    int i = blockIdx.x * 256 + threadIdx.x;
    if (i < BATCH * 64 * 72) stats[i] = 0.f;
}

// ---------------------------------------------------------------------------
// K2 v6: stats heads 0..31 via MFMA GRAM. Lane (c=lane&15, kg=lane>>4)
// streams 8 px of channel c per 32-px step; same short8 is both A-row c and
// B-col c of mfma_f32_16x16x32_bf16 -> D = Gram (16x16); rows 8..15 x cols
// 0..7 = vk. ksum via B=ones MFMA. bf16 hi/lo 3-pass ~f32. No LDS/barriers.
// grid (32 h, 4 ps, 16 b) = 2048 blocks.
// ---------------------------------------------------------------------------
__global__ __launch_bounds__(256) void attn_stats_direct(
    const float* __restrict__ KV,
    float* __restrict__ stats)
{
    const int h = blockIdx.x, ps = blockIdx.y, b = blockIdx.z;
    const int tid = threadIdx.x;
    const int lane = tid & 63, wv = tid >> 6;
    const int c  = lane & 15;
    const int kg = lane >> 4;

    const float* cb = KV + ((size_t)b * 512 + h * 16 + c) * HW
                    + ps * 1024 + wv * 256 + kg * 8;

    floatx4 accg = (floatx4)0.f;     // gram
    floatx4 accs = (floatx4)0.f;     // rowsums (ksum in rows 0..7)
    short8 ones;
    #pragma unroll
    for (int j = 0; j < 8; j++) ones[j] = (short)0x3F80;  // bf16 1.0

    for (int st = 0; st < 8; st++) {
        float4 f0 = *reinterpret_cast<const float4*>(cb + st * 32);
        float4 f1 = *reinterpret_cast<const float4*>(cb + st * 32 + 4);
        float v[8] = {f0.x, f0.y, f0.z, f0.w, f1.x, f1.y, f1.z, f1.w};
        short8 hi, lo;
        #pragma unroll
        for (int j = 0; j < 8; j++) {
            short hh = f32_to_bf16(v[j]);
            hi[j] = hh;
            lo[j] = f32_to_bf16(v[j] - bf16_to_f32(hh));
        }
        accg = __builtin_amdgcn_mfma_f32_16x16x32_bf16(hi, hi, accg, 0, 0, 0);
        accg = __builtin_amdgcn_mfma_f32_16x16x32_bf16(hi, lo, accg, 0, 0, 0);
        accg = __builtin_amdgcn_mfma_f32_16x16x32_bf16(lo, hi, accg, 0, 0, 0);
        accs = __builtin_amdgcn_mfma_f32_16x16x32_bf16(hi, ones, accs, 0, 0, 0);
        accs = __builtin_amdgcn_mfma_f32_16x16x32_bf16(lo, ones, accs, 0, 0, 0);
    }

    // D layout: col = lane&15, row = (lane>>4)*4 + r
    float* sb = stats + ((size_t)b * 64 + h) * 72;
    if (c < 8 && kg >= 2) {           // rows 8..15 (v), cols 0..7 (k)
        #pragma unroll
        for (int r = 0; r < 4; r++)
            atomicAdd(sb + ((kg - 2) * 4 + r) * 8 + c, accg[r]);
    }
    if (c == 0 && kg < 2) {           // ksum rows 0..7, any col -> col 0
        #pragma unroll
        for (int r = 0; r < 4; r++)
            atomicAdd(sb + 64 + kg * 4 + r, accs[r]);
    }
}

// ---------------------------------------------------------------------------
// K3 v7: stats heads 32..63 = rolling-window 5x5 dwconv fused with MFMA GRAM.
// Each input row is loaded ONCE (12 rows/strip) and scattered into the <=5
// live output-row accumulators out[5][8] (rotating slots, full unroll ->
// compile-time indices). When input li lands, output li-4 completes ->
// affine -> relu(k) -> bf16 hi/lo -> 5 Gram/ksum MFMAs -> slot reset.
// No LDS, no barriers. grid (32 hp, 2 ysb, 16 b) = 1024 blocks.
// ---------------------------------------------------------------------------
__global__ __launch_bounds__(256) void attn_stats_dw(
    const float* __restrict__ KV,
    const float* __restrict__ dww, const float* __restrict__ dwb,
    const float* __restrict__ pww, const float* __restrict__ pwb,
    float* __restrict__ stats)
{
    const int hp = blockIdx.x, ysb = blockIdx.y, b = blockIdx.z;
    const int tid = threadIdx.x;
    const int lane = tid & 63, wv = tid >> 6;
    const int c  = lane & 15;
    const int kg = lane >> 4;
    const int creal = hp * 24 + 8 + c;

    float wt[25];
    #pragma unroll
    for (int i = 0; i < 25; i++) wt[i] = dww[creal * 25 + i];
    const float pw = pww[creal];
    const float pb = pw * dwb[creal] + pwb[creal];

    const float* cb = KV + ((size_t)b * 512 + hp * 16 + c) * HW;
    const int ybase = ysb * 32 + wv * 8;

    floatx4 accg = (floatx4)0.f;
    floatx4 accs = (floatx4)0.f;
    short8 ones;
    #pragma unroll
    for (int j = 0; j < 8; j++) ones[j] = (short)0x3F80;

    #pragma unroll
    for (int xh = 0; xh < 2; xh++) {
        const int x0 = xh * 32 + kg * 8;
        const float mL = (x0 == 0)  ? 0.f : 1.f;
        const float mR = (x0 == 56) ? 0.f : 1.f;
        const int colL = (x0 == 0)  ? 0  : x0 - 4;
        const int colR = (x0 == 56) ? 56 : x0 + 8;

        float out[5][8] = {};
        #pragma unroll
        for (int li = 0; li < 12; li++) {
            const int ry = ybase + li - 2;
            float4 Q0 = {0,0,0,0}, Q1 = {0,0,0,0}, Q2 = {0,0,0,0}, Q3 = {0,0,0,0};
            if (ry >= 0 && ry < WIMG) {          // wave-uniform
                const float* rp = cb + ry * WIMG;
                Q0 = *reinterpret_cast<const float4*>(rp + colL);
                Q1 = *reinterpret_cast<const float4*>(rp + x0);
                Q2 = *reinterpret_cast<const float4*>(rp + x0 + 4);
                Q3 = *reinterpret_cast<const float4*>(rp + colR);
            }
            float win[12] = {Q0.z * mL, Q0.w * mL,
                             Q1.x, Q1.y, Q1.z, Q1.w,
                             Q2.x, Q2.y, Q2.z, Q2.w,
                             Q3.x * mR, Q3.y * mR};
            // scatter into live output rows lo = li-4..li
            #pragma unroll
            for (int rr = 0; rr < 5; rr++) {
                const int lo = li - rr;
                if (lo >= 0 && lo < 8) {
                    #pragma unroll
                    for (int kx = 0; kx < 5; kx++) {
                        float w5 = wt[rr * 5 + kx];
                        #pragma unroll
                        for (int j = 0; j < 8; j++)
                            out[lo % 5][j] += w5 * win[j + kx];
                    }
                }
            }
            // finalize completed output row lo = li-4
            const int lod = li - 4;
            if (lod >= 0 && lod < 8) {
                short8 hib, lob;
                #pragma unroll
                for (int j = 0; j < 8; j++) {
                    float v = out[lod % 5][j] * pw + pb;
                    float vr = fmaxf(v, 0.f);
                    v = (c < 8) ? vr : v;        // relu k-channels only
                    short hh = f32_to_bf16(v);
                    hib[j] = hh;
                    lob[j] = f32_to_bf16(v - bf16_to_f32(hh));
                }
                accg = __builtin_amdgcn_mfma_f32_16x16x32_bf16(hib, hib, accg, 0, 0, 0);
                accg = __builtin_amdgcn_mfma_f32_16x16x32_bf16(hib, lob, accg, 0, 0, 0);
                accg = __builtin_amdgcn_mfma_f32_16x16x32_bf16(lob, hib, accg, 0, 0, 0);
                accs = __builtin_amdgcn_mfma_f32_16x16x32_bf16(hib, ones, accs, 0, 0, 0);
                accs = __builtin_amdgcn_mfma_f32_16x16x32_bf16(lob, ones, accs, 0, 0, 0);
                #pragma unroll
                for (int j = 0; j < 8; j++) out[lod % 5][j] = 0.f;
            }
        }
    }

    float* sb = stats + ((size_t)b * 64 + 32 + hp) * 72;
    if (c < 8 && kg >= 2) {
        #pragma unroll
        for (int r = 0; r < 4; r++)
            atomicAdd(sb + ((kg - 2) * 4 + r) * 8 + c, accg[r]);
    }
    if (c == 0 && kg < 2) {
        #pragma unroll
        for (int r = 0; r < 4; r++)
            atomicAdd(sb + 64 + kg * 4 + r, accs[r]);
    }
}

// ---------------------------------------------------------------------------
// K3b v7: Qagg = rolling-window 5x5 dwconv + affine of q channels; each input
// row loaded once, out[5][8] rotating slots, finalize -> 2x float4 store.
// Lane (c=lane&7, g=lane>>3) covers 8 px of channel c; wave = full 64-px row
// x 8 channels. grid (32 hb, 2 ysb, 16 b) = 1024 blocks. Raw out (relu K5).
// ---------------------------------------------------------------------------
__global__ __launch_bounds__(256) void q_dwconv(
    const float* __restrict__ Qf,     // (B,256,HW) packed q
    const float* __restrict__ dww, const float* __restrict__ dwb,
    const float* __restrict__ pww, const float* __restrict__ pwb,
    float* __restrict__ Qagg)         // (B,256,HW) packed dwconv(q)
{
    const int hb = blockIdx.x, ysb = blockIdx.y, b = blockIdx.z;
    const int tid = threadIdx.x;
    const int lane = tid & 63, wv = tid >> 6;
    const int c = lane & 7;
    const int g = lane >> 3;          // 0..7
    const int x0 = g * 8;
    const int creal = hb * 24 + c;

    float wt[25];
    #pragma unroll
    for (int i = 0; i < 25; i++) wt[i] = dww[creal * 25 + i];
    const float pw = pww[creal];
    const float pb = pw * dwb[creal] + pwb[creal];

    const float mL = (x0 == 0)  ? 0.f : 1.f;
    const float mR = (x0 == 56) ? 0.f : 1.f;
    const int colL = (x0 == 0)  ? 0  : x0 - 4;
    const int colR = (x0 == 56) ? 56 : x0 + 8;

    const float* cbase = Qf   + ((size_t)b * 256 + hb * 8 + c) * HW;
    float*       obase = Qagg + ((size_t)b * 256 + hb * 8 + c) * HW;
    const int ybase = ysb * 32 + wv * 8;

    float out[5][8] = {};
    #pragma unroll
    for (int li = 0; li < 12; li++) {
        const int ry = ybase + li - 2;
        float4 Q0 = {0,0,0,0}, Q1 = {0,0,0,0}, Q2 = {0,0,0,0}, Q3 = {0,0,0,0};
        if (ry >= 0 && ry < WIMG) {
            const float* rp = cbase + ry * WIMG;
            Q0 = *reinterpret_cast<const float4*>(rp + colL);
            Q1 = *reinterpret_cast<const float4*>(rp + x0);
            Q2 = *reinterpret_cast<const float4*>(rp + x0 + 4);
            Q3 = *reinterpret_cast<const float4*>(rp + colR);
        }
        float win[12] = {Q0.z * mL, Q0.w * mL,
                         Q1.x, Q1.y, Q1.z, Q1.w,
                         Q2.x, Q2.y, Q2.z, Q2.w,
                         Q3.x * mR, Q3.y * mR};
        #pragma unroll
        for (int rr = 0; rr < 5; rr++) {
            const int lo = li - rr;
            if (lo >= 0 && lo < 8) {
                #pragma unroll
                for (int kx = 0; kx < 5; kx++) {
                    float w5 = wt[rr * 5 + kx];
                    #pragma unroll
                    for (int j = 0; j < 8; j++)
                        out[lo % 5][j] += w5 * win[j + kx];
                }
            }
        }
        const int lod = li - 4;
        if (lod >= 0 && lod < 8) {
            float4 o0 = {out[lod % 5][0] * pw + pb, out[lod % 5][1] * pw + pb,
                         out[lod % 5][2] * pw + pb, out[lod % 5][3] * pw + pb};
            float4 o1 = {out[lod % 5][4] * pw + pb, out[lod % 5][5] * pw + pb,
                         out[lod % 5][6] * pw + pb, out[lod % 5][7] * pw + pb};
            float* dst = obase + (ybase + lod) * WIMG + x0;
            *reinterpret_cast<float4*>(dst)     = o0;
            *reinterpret_cast<float4*>(dst + 4) = o1;
            #pragma unroll
            for (int j = 0; j < 8; j++) out[lod % 5][j] = 0.f;
        }
    }
}

// ---------------------------------------------------------------------------
// K4 v2: fold proj weights with vk, COLUMN-RESCALED by g_e = ksum_e + eps.
// Parallelized over head-groups: grid (8 hg, 16 b) = 128 blocks.
// ---------------------------------------------------------------------------
__global__ __launch_bounds__(256) void build_M(
    const float* __restrict__ stats,   // (B,64,72)
    const float* __restrict__ projw,   // (256,512)
    _Float16* __restrict__ Mhi,        // (B,256,512)
    _Float16* __restrict__ Mlo)
{
    const int hg = blockIdx.x;         // head group (8 heads)
    const int b  = blockIdx.y;
    const int tid = threadIdx.x;

    __shared__ float svk[8][64];
    __shared__ float sginv[8][8];

    for (int i = tid; i < 8 * 64; i += 256) {
        int h = i >> 6;
        svk[h][i & 63] = stats[((size_t)b * 64 + hg * 8 + h) * 72 + (i & 63)];
    }
    if (tid < 64)
        sginv[tid >> 3][tid & 7] =
            1.0f / (stats[((size_t)b * 64 + hg * 8 + (tid >> 3)) * 72 + 64 + (tid & 7)] + EPS_F);
    __syncthreads();

    const float* wr = projw + (size_t)tid * 512 + hg * 64;
    #pragma unroll
    for (int hh = 0; hh < 8; hh++) {
        float wv[8];
        float4 a0 = *reinterpret_cast<const float4*>(wr + hh * 8);
        float4 a1 = *reinterpret_cast<const float4*>(wr + hh * 8 + 4);
        wv[0]=a0.x; wv[1]=a0.y; wv[2]=a0.z; wv[3]=a0.w;
        wv[4]=a1.x; wv[5]=a1.y; wv[6]=a1.z; wv[7]=a1.w;
        union { _Float16 h8[8]; uint4 u; } hi, lo;
        #pragma unroll
        for (int e = 0; e < 8; e++) {
            float s = 0.f;
            #pragma unroll
            for (int d = 0; d < 8; d++) s += wv[d] * svk[hh][d * 8 + e];
            s *= sginv[hh][e];
            _Float16 sh = (_Float16)s;
            hi.h8[e] = sh;
            lo.h8[e] = (_Float16)(s - (float)sh);
        }
        size_t off = ((size_t)b * 256 + tid) * 512 + hg * 64 + hh * 8;
        *reinterpret_cast<uint4*>(Mhi + off) = hi.u;
        *reinterpret_cast<uint4*>(Mlo + off) = lo.u;
    }
}

// ---------------------------------------------------------------------------
// K5: 128-px tile, 4 barriers total. Qt_e = QSCALE*g_e*q_e/den (bounded),
// f16; two half-K phases (heads 0..31 from Qf, 32..63 from Qagg), each a
// 2-pass hi/lo f16 MFMA GEMM (256ch x 128px). LDS ~70 KB -> 2 blocks/CU.
// ---------------------------------------------------------------------------
__global__ __launch_bounds__(256) void attn_proj_mfma(
    const float* __restrict__ Qf,      // (B,256,HW) packed q (>=0)
    const float* __restrict__ Qagg,    // (B,256,HW) packed dwconv(q), raw
    const float* __restrict__ stats,   // ksum at [64..71]
    const _Float16* __restrict__ Mhi,  // (B,256,512)
    const _Float16* __restrict__ Mlo,
    const float* __restrict__ scale, const float* __restrict__ bias,
    float* __restrict__ out)           // (B,256,HW)
{
    const int pt  = blockIdx.x * 128;
    const int b   = blockIdx.y;
    const int tid = threadIdx.x;
    const int wv  = tid >> 6, lane = tid & 63;

    __shared__ _Float16 Qt[128][264];     // 67.6 KB half-K [px][k]
    __shared__ float    ksums[64][8];     // 2 KB

    for (int i = tid; i < 512; i += 256)
        ksums[i >> 3][i & 7] = stats[((size_t)b * 64 + (i >> 3)) * 72 + 64 + (i & 7)];
    __syncthreads();

    const int pxl = tid & 127;            // local pixel for Qt build
    const int eg  = (tid >> 7) * 4;       // 4 e's per thread
    const int u = lane & 15, q8 = (lane >> 4) * 8;
    const int quad = lane >> 4;

    floatx4 acc[4][8];
    #pragma unroll
    for (int i = 0; i < 4; i++)
        #pragma unroll
        for (int j = 0; j < 8; j++) acc[i][j] = (floatx4)0.f;

    // ============ phase A: heads 0..31 (q direct from Qf, >=0) ============
    for (int h = 0; h < 32; h++) {
        const float* qp = Qf + ((size_t)b * 256 + h * 8) * HW + pt + pxl;
        float qv[8];
        #pragma unroll
        for (int e = 0; e < 8; e++) qv[e] = qp[(size_t)e * HW];
        float den = EPS_F;
        #pragma unroll
        for (int e = 0; e < 8; e++) den += ksums[h][e] * qv[e];
        float rd = QSCALE / den;
        union { _Float16 h4[4]; uint2 u2; } pk;
        #pragma unroll
        for (int j = 0; j < 4; j++) {
            float g = ksums[h][eg + j] + EPS_F;
            pk.h4[j] = (_Float16)fminf(qv[eg + j] * g * rd, 60000.f);
        }
        *reinterpret_cast<uint2*>(&Qt[pxl][h * 8 + eg]) = pk.u2;
    }
    __syncthreads();

    for (int ks = 0; ks < 8; ks++) {
        half8 ah[4], al[4], bf[8];
        #pragma unroll
        for (int mt = 0; mt < 4; mt++) {
            size_t moff = ((size_t)b * 256 + wv * 64 + mt * 16 + u) * 512 + ks * 32 + q8;
            ah[mt] = *reinterpret_cast<const half8*>(Mhi + moff);
            al[mt] = *reinterpret_cast<const half8*>(Mlo + moff);
        }
        #pragma unroll
        for (int nt = 0; nt < 8; nt++)
            bf[nt] = *reinterpret_cast<const half8*>(&Qt[nt * 16 + u][ks * 32 + q8]);
        #pragma unroll
        for (int mt = 0; mt < 4; mt++)
            #pragma unroll
            for (int nt = 0; nt < 8; nt++) {
                acc[mt][nt] = __builtin_amdgcn_mfma_f32_16x16x32_f16(ah[mt], bf[nt], acc[mt][nt], 0, 0, 0);
                acc[mt][nt] = __builtin_amdgcn_mfma_f32_16x16x32_f16(al[mt], bf[nt], acc[mt][nt], 0, 0, 0);
            }
    }
    __syncthreads();

    // ============ phase B: heads 32..63 (q from Qagg, needs relu) ==========
    for (int h = 32; h < 64; h++) {
        const int hb = h - 32;
        const float* qp = Qagg + ((size_t)b * 256 + hb * 8) * HW + pt + pxl;
        float qv[8];
        #pragma unroll
        for (int e = 0; e < 8; e++) qv[e] = fmaxf(qp[(size_t)e * HW], 0.f);
        float den = EPS_F;
        #pragma unroll
        for (int e = 0; e < 8; e++) den += ksums[h][e] * qv[e];
        float rd = QSCALE / den;
        union { _Float16 h4[4]; uint2 u2; } pk;
        #pragma unroll
        for (int j = 0; j < 4; j++) {
            float g = ksums[h][eg + j] + EPS_F;
            pk.h4[j] = (_Float16)fminf(qv[eg + j] * g * rd, 60000.f);
        }
        *reinterpret_cast<uint2*>(&Qt[pxl][hb * 8 + eg]) = pk.u2;
    }
    __syncthreads();

    for (int ks = 0; ks < 8; ks++) {
        half8 ah[4], al[4], bf[8];
        #pragma unroll
        for (int mt = 0; mt < 4; mt++) {
            size_t moff = ((size_t)b * 256 + wv * 64 + mt * 16 + u) * 512 + 256 + ks * 32 + q8;
            ah[mt] = *reinterpret_cast<const half8*>(Mhi + moff);
            al[mt] = *reinterpret_cast<const half8*>(Mlo + moff);
        }
        #pragma unroll
        for (int nt = 0; nt < 8; nt++)
            bf[nt] = *reinterpret_cast<const half8*>(&Qt[nt * 16 + u][ks * 32 + q8]);
        #pragma unroll
        for (int mt = 0; mt < 4; mt++)
            #pragma unroll
            for (int nt = 0; nt < 8; nt++) {
                acc[mt][nt] = __builtin_amdgcn_mfma_f32_16x16x32_f16(ah[mt], bf[nt], acc[mt][nt], 0, 0, 0);
                acc[mt][nt] = __builtin_amdgcn_mfma_f32_16x16x32_f16(al[mt], bf[nt], acc[mt][nt], 0, 0, 0);
            }
    }

    #pragma unroll
    for (int mt = 0; mt < 4; mt++)
        #pragma unroll
        for (int r = 0; r < 4; r++) {
            int c = wv * 64 + mt * 16 + quad * 4 + r;
            float s = scale[c] * (1.0f / QSCALE);
            float bi = bias[c];
            #pragma unroll
            for (int nt = 0; nt < 8; nt++) {
                int px = pt + nt * 16 + u;
                out[((size_t)b * COUT + c) * HW + px] = fmaxf(acc[mt][nt][r] * s + bi, 0.f);
            }
        }
}

// ---------------------------------------------------------------------------
extern "C" void kernel_launch(void* const* d_in, const int* in_sizes, int n_in,
                              void* d_out, int out_size, void* d_ws, size_t ws_size,
                              hipStream_t stream)
{
    const float* x      = (const float*)d_in[0];
    const float* qkv_w  = (const float*)d_in[1];
    const float* qkv_s  = (const float*)d_in[2];
    const float* qkv_b  = (const float*)d_in[3];
    const float* dw_w   = (const float*)d_in[4];
    const float* dw_b   = (const float*)d_in[5];
    const float* pw_w   = (const float*)d_in[6];
    const float* pw_b   = (const float*)d_in[7];
    const float* proj_w = (const float*)d_in[8];
    const float* proj_s = (const float*)d_in[9];
    const float* proj_b = (const float*)d_in[10];
    float* out = (float*)d_out;

    // ws layout (exactly the PROVEN 192.3 MiB):
    //   [0,128 MiB)    KV f32 — dead after K2/K3; reused: Mhi(4)+Mlo(4)+Qagg(64)
    //   [128,192 MiB)  Qf f32
    //   [192 MiB,+288K) stats
    float*    KV    = (float*)d_ws;
    _Float16* Mhi   = (_Float16*)d_ws;                          // +0
    _Float16* Mlo   = Mhi + (size_t)BATCH * 256 * 512;          // +4 MiB
    float*    Qagg  = (float*)(Mlo + (size_t)BATCH * 256 * 512);// +8 MiB (64 MiB)
    float*    Qf    = KV + (size_t)BATCH * 512 * HW;            // +128 MiB
    float*    stats = Qf + (size_t)BATCH * 256 * HW;            // +192 MiB

    conv_q_f32<<<dim3(HW / 128, 2, BATCH), 256, 0, stream>>>(
        x, qkv_w, qkv_s, qkv_b, Qf);

    conv_kv_mfma<<<dim3(4, 32, BATCH), 256, 0, stream>>>(
        x, qkv_w, qkv_s, qkv_b, KV);

    // zero stats before the atomic-reduce stats kernels
    zero_stats<<<dim3((BATCH * 64 * 72 + 255) / 256), 256, 0, stream>>>(stats);

    attn_stats_direct<<<dim3(32, 4, BATCH), 256, 0, stream>>>(KV, stats);

    attn_stats_dw<<<dim3(32, 2, BATCH), 256, 0, stream>>>(
        KV, dw_w, dw_b, pw_w, pw_b, stats);

    // after K2/K3: KV region dead -> safe to overwrite with Qagg / M
    q_dwconv<<<dim3(32, 2, BATCH), 256, 0, stream>>>(
        Qf, dw_w, dw_b, pw_w, pw_b, Qagg);

    build_M<<<dim3(8, BATCH), 256, 0, stream>>>(stats, proj_w, Mhi, Mlo);

    attn_proj_mfma<<<dim3(HW / 128, BATCH), 256, 0, stream>>>(
        Qf, Qagg, stats, Mhi, Mlo, proj_s, proj_b, out);
}

// Round 13
// 557.685 us; speedup vs baseline: 1.0813x; 1.0049x over previous
//
#include <hip/hip_runtime.h>

#define HW    4096
#define WIMG  64
#define CIN   256
#define C3    768
#define COUT  256
#define BATCH 16
#define NHB   32
#define EPS_F 1e-5f
#define QSCALE 1024.0f   // pow2: exactly undone in epilogue
#define WSCALE 256.0f    // pow2 weight prescale (f16 lo stays normal); undone in epilogue

typedef __attribute__((ext_vector_type(8))) short    short8;
typedef __attribute__((ext_vector_type(8))) _Float16 half8;
typedef __attribute__((ext_vector_type(2))) __fp16   fp16x2;  // cvt_pkrtz return type
typedef __attribute__((ext_vector_type(4))) float    floatx4;

__device__ inline short f32_to_bf16(float f) {
    unsigned u = __builtin_bit_cast(unsigned, f);
    unsigned r = u + 0x7fffu + ((u >> 16) & 1u);
    return (short)(r >> 16);
}
__device__ inline float bf16_to_f32(short s) {
    return __builtin_bit_cast(float, ((unsigned)(unsigned short)s) << 16);
}

// f32[8] -> f16 hi/lo split via v_cvt_pkrtz (1 instr per 2 elems per pack).
// hi = rtz(f); lo = rtz(f - hi). ~3 VALU/elem vs ~8.5 for bf16 split, and
// 11+11 mantissa bits (better than bf16's 8+8).
__device__ __forceinline__ void split8_f16(const float* f, half8& hi, half8& lo) {
    #pragma unroll
    for (int p = 0; p < 4; p++) {
        fp16x2 h = __builtin_amdgcn_cvt_pkrtz(f[2 * p], f[2 * p + 1]);
        fp16x2 l = __builtin_amdgcn_cvt_pkrtz(f[2 * p]     - (float)h.x,
                                              f[2 * p + 1] - (float)h.y);
        hi[2 * p] = (_Float16)h.x; hi[2 * p + 1] = (_Float16)h.y;
        lo[2 * p] = (_Float16)l.x; lo[2 * p + 1] = (_Float16)l.y;
    }
}

// async global->LDS, 4B per lane. lds dest must be wave-uniform base.
__device__ __forceinline__ void async_copy_f32(const float* g, float* l) {
    __builtin_amdgcn_global_load_lds(
        (const __attribute__((address_space(1))) void*)g,
        (__attribute__((address_space(3))) void*)l, 4, 0, 0);
}

// ---------------------------------------------------------------------------
// K1a v4: q channels (packed 256) of qkv 1x1 conv, f32 VALU GEMM.
// 128x128 tile, 8x8 per thread. q stays f32 (eps-denominator cliff).
// Xs via global_load_lds; Ws via float4-along-k loads; Ws[16][132] padding.
// ---------------------------------------------------------------------------
__global__ __launch_bounds__(256) void conv_q_f32(
    const float* __restrict__ in,     // (B, 256, HW)
    const float* __restrict__ w,      // (768, 256)
    const float* __restrict__ scale,
    const float* __restrict__ bias,
    float* __restrict__ Qf)           // (B, 256, HW) packed q
{
    const int pt  = blockIdx.x * 128;
    const int ct  = blockIdx.y * 128;
    const int b   = blockIdx.z;
    const int tid = threadIdx.x;
    const int lane = tid & 63, wv4 = tid >> 6;
    const int tx  = tid & 15;         // px groups tx*4 and 64+tx*4
    const int ty  = tid >> 4;         // ch groups ty*4 and 64+ty*4

    __shared__ float Ws[16][132];     // padded: conflict-free staging writes
    __shared__ float Xs[16][128];

    float acc[8][8] = {};
    const float* xb = in + (size_t)b * CIN * HW + pt;

    // Ws load mapping (k0-invariant): elem in {tid, tid+256};
    // c = elem>>2, kq = elem&3; float4 covers k = kq*4..kq*4+3.
    const int c0 = tid >> 2,        kq0 = tid & 3;
    const int c1 = (tid + 256) >> 2;                 // kq1 == kq0
    const int cp0 = ct + c0, cp1 = ct + c1;
    const int creal0 = (cp0 >> 3) * 24 + (cp0 & 7);
    const int creal1 = (cp1 >> 3) * 24 + (cp1 & 7);
    const float* wp0 = w + (size_t)creal0 * CIN + kq0 * 4;
    const float* wp1 = w + (size_t)creal1 * CIN + kq0 * 4;

    for (int k0 = 0; k0 < CIN; k0 += 16) {
        // ---- stage Ws: 2 float4 global loads + 8 scalar LDS writes ----
        float4 wa = *reinterpret_cast<const float4*>(wp0 + k0);
        float4 wb = *reinterpret_cast<const float4*>(wp1 + k0);
        Ws[kq0 * 4 + 0][c0] = wa.x; Ws[kq0 * 4 + 1][c0] = wa.y;
        Ws[kq0 * 4 + 2][c0] = wa.z; Ws[kq0 * 4 + 3][c0] = wa.w;
        Ws[kq0 * 4 + 0][c1] = wb.x; Ws[kq0 * 4 + 1][c1] = wb.y;
        Ws[kq0 * 4 + 2][c1] = wb.z; Ws[kq0 * 4 + 3][c1] = wb.w;
        // ---- stage Xs: async global->LDS, wave wv4 rows 4*wv4..4*wv4+3 ----
        #pragma unroll
        for (int r = 0; r < 8; r++) {
            int row  = wv4 * 4 + (r >> 1);
            int half = (r & 1) * 64;
            async_copy_f32(xb + (size_t)(k0 + row) * HW + half + lane,
                           &Xs[row][half]);
        }
        __syncthreads();              // drains vmcnt+lgkmcnt (compiler)

        #pragma unroll
        for (int kk = 0; kk < 16; kk++) {
            float4 a0 = *reinterpret_cast<const float4*>(&Ws[kk][ty * 4]);
            float4 a1 = *reinterpret_cast<const float4*>(&Ws[kk][64 + ty * 4]);
            float4 b0 = *reinterpret_cast<const float4*>(&Xs[kk][tx * 4]);
            float4 b1 = *reinterpret_cast<const float4*>(&Xs[kk][64 + tx * 4]);
            float a[8] = {a0.x, a0.y, a0.z, a0.w, a1.x, a1.y, a1.z, a1.w};
            float bb[8] = {b0.x, b0.y, b0.z, b0.w, b1.x, b1.y, b1.z, b1.w};
            #pragma unroll
            for (int i = 0; i < 8; i++)
                #pragma unroll
                for (int j = 0; j < 8; j++)
                    acc[i][j] += a[i] * bb[j];
        }
        __syncthreads();
    }

    #pragma unroll
    for (int i = 0; i < 8; i++) {
        int cp = ct + (i < 4 ? ty * 4 + i : 64 + ty * 4 + (i - 4));
        int creal = (cp >> 3) * 24 + (cp & 7);
        float s = scale[creal];
        float bi = bias[creal];
        float4 v0, v1;
        v0.x = fmaxf(acc[i][0] * s + bi, 0.f);
        v0.y = fmaxf(acc[i][1] * s + bi, 0.f);
        v0.z = fmaxf(acc[i][2] * s + bi, 0.f);
        v0.w = fmaxf(acc[i][3] * s + bi, 0.f);
        v1.x = fmaxf(acc[i][4] * s + bi, 0.f);
        v1.y = fmaxf(acc[i][5] * s + bi, 0.f);
        v1.z = fmaxf(acc[i][6] * s + bi, 0.f);
        v1.w = fmaxf(acc[i][7] * s + bi, 0.f);
        float* dst = Qf + ((size_t)b * 256 + cp) * HW + pt;
        *reinterpret_cast<float4*>(dst + tx * 4)      = v0;
        *reinterpret_cast<float4*>(dst + 64 + tx * 4) = v1;
    }
}

// ---------------------------------------------------------------------------
// K1b v3: k/v channels (packed 512) via f16 hi/lo 3-pass MFMA (pkrtz split,
// ~2.8x less conversion VALU than bf16 split, 22-bit effective mantissa).
// Weights prescaled x256 (pow2) so lo stays f16-normal; epilogue divides.
// Packed c' in [0,512): real = (c'>>4)*24 + 8 + (c'&15). Out f32.
// ---------------------------------------------------------------------------
__global__ __launch_bounds__(256) void conv_kv_mfma(
    const float* __restrict__ x,
    const float* __restrict__ w,
    const float* __restrict__ scale,
    const float* __restrict__ bias,
    float* __restrict__ KV)           // (B, 512, HW) packed k/v, f32
{
    const int ct = blockIdx.x, pt = blockIdx.y, b = blockIdx.z;
    const int tid  = threadIdx.x;
    const int wv   = tid >> 6, lane = tid & 63;
    const int u    = lane & 15, q8 = (lane >> 4) * 8;
    const int chb  = ct * 128 + (wv >> 1) * 64;
    const int pxb  = pt * 128 + (wv & 1) * 64;

    floatx4 acc[4][4];
    #pragma unroll
    for (int i = 0; i < 4; i++)
        #pragma unroll
        for (int j = 0; j < 4; j++) acc[i][j] = (floatx4)0.f;

    for (int kc = 0; kc < 8; kc++) {
        const int k0 = kc * 32 + q8;
        half8 ahi[4], alo[4];
        #pragma unroll
        for (int mt = 0; mt < 4; mt++) {
            int cp = chb + mt * 16 + u;
            int creal = (cp >> 4) * 24 + 8 + (cp & 15);
            const float* wp = w + (size_t)creal * CIN + k0;
            float g[8];
            #pragma unroll
            for (int j = 0; j < 8; j++) g[j] = wp[j] * WSCALE;
            split8_f16(g, ahi[mt], alo[mt]);
        }
        half8 bhi[4], blo[4];
        #pragma unroll
        for (int nt = 0; nt < 4; nt++) {
            const float* xp = x + ((size_t)b * CIN + k0) * HW + pxb + nt * 16 + u;
            float g[8];
            #pragma unroll
            for (int j = 0; j < 8; j++) g[j] = xp[(size_t)j * HW];
            split8_f16(g, bhi[nt], blo[nt]);
        }
        #pragma unroll
        for (int mt = 0; mt < 4; mt++)
            #pragma unroll
            for (int nt = 0; nt < 4; nt++) {
                acc[mt][nt] = __builtin_amdgcn_mfma_f32_16x16x32_f16(ahi[mt], bhi[nt], acc[mt][nt], 0, 0, 0);
                acc[mt][nt] = __builtin_amdgcn_mfma_f32_16x16x32_f16(ahi[mt], blo[nt], acc[mt][nt], 0, 0, 0);
                acc[mt][nt] = __builtin_amdgcn_mfma_f32_16x16x32_f16(alo[mt], bhi[nt], acc[mt][nt], 0, 0, 0);
            }
    }

    const int quad = lane >> 4;
    #pragma unroll
    for (int mt = 0; mt < 4; mt++)
        #pragma unroll
        for (int r = 0; r < 4; r++) {
            int cp = chb + mt * 16 + quad * 4 + r;
            int creal = (cp >> 4) * 24 + 8 + (cp & 15);
            float s = scale[creal] * (1.0f / WSCALE), bi = bias[creal];
            #pragma unroll
            for (int nt = 0; nt < 4; nt++) {
                int px = pxb + nt * 16 + u;
                KV[((size_t)b * 512 + cp) * HW + px] = fmaxf(acc[mt][nt][r] * s + bi, 0.f);
            }
        }
}

// ---------------------------------------------------------------------------
// K0z: zero the stats region (atomic consumers below; re-entrant per launch).
// ---------------------------------------------------------------------------
__global__ __launch_bounds__(256) void zero_stats(float* __restrict__ stats)
{
    int i = blockIdx.x * 256 + threadIdx.x;
    if (i < BATCH * 64 * 72) stats[i] = 0.f;
}

// ---------------------------------------------------------------------------
// K2 v7: stats heads 0..31 via MFMA GRAM, f16 hi/lo (pkrtz split).
// Lane (c=lane&15, kg=lane>>4) streams 8 px of channel c per 32-px step;
// same half8 is both A-row c and B-col c -> D = Gram; rows 8..15 x cols
// 0..7 = vk. ksum via B=ones MFMA. No LDS/barriers.
// grid (32 h, 4 ps, 16 b) = 2048 blocks.
// ---------------------------------------------------------------------------
__global__ __launch_bounds__(256) void attn_stats_direct(
    const float* __restrict__ KV,
    float* __restrict__ stats)
{
    const int h = blockIdx.x, ps = blockIdx.y, b = blockIdx.z;
    const int tid = threadIdx.x;
    const int lane = tid & 63, wv = tid >> 6;
    const int c  = lane & 15;
    const int kg = lane >> 4;

    const float* cb = KV + ((size_t)b * 512 + h * 16 + c) * HW
                    + ps * 1024 + wv * 256 + kg * 8;

    floatx4 accg = (floatx4)0.f;     // gram
    floatx4 accs = (floatx4)0.f;     // rowsums (ksum in rows 0..7)
    half8 ones;
    #pragma unroll
    for (int j = 0; j < 8; j++) ones[j] = (_Float16)1.0f;

    for (int st = 0; st < 8; st++) {
        float4 f0 = *reinterpret_cast<const float4*>(cb + st * 32);
        float4 f1 = *reinterpret_cast<const float4*>(cb + st * 32 + 4);
        float v[8] = {f0.x, f0.y, f0.z, f0.w, f1.x, f1.y, f1.z, f1.w};
        half8 hi, lo;
        split8_f16(v, hi, lo);
        accg = __builtin_amdgcn_mfma_f32_16x16x32_f16(hi, hi, accg, 0, 0, 0);
        accg = __builtin_amdgcn_mfma_f32_16x16x32_f16(hi, lo, accg, 0, 0, 0);
        accg = __builtin_amdgcn_mfma_f32_16x16x32_f16(lo, hi, accg, 0, 0, 0);
        accs = __builtin_amdgcn_mfma_f32_16x16x32_f16(hi, ones, accs, 0, 0, 0);
        accs = __builtin_amdgcn_mfma_f32_16x16x32_f16(lo, ones, accs, 0, 0, 0);
    }

    // D layout: col = lane&15, row = (lane>>4)*4 + r  (dtype-independent)
    float* sb = stats + ((size_t)b * 64 + h) * 72;
    if (c < 8 && kg >= 2) {           // rows 8..15 (v), cols 0..7 (k)
        #pragma unroll
        for (int r = 0; r < 4; r++)
            atomicAdd(sb + ((kg - 2) * 4 + r) * 8 + c, accg[r]);
    }
    if (c == 0 && kg < 2) {           // ksum rows 0..7, any col -> col 0
        #pragma unroll
        for (int r = 0; r < 4; r++)
            atomicAdd(sb + 64 + kg * 4 + r, accs[r]);
    }
}

// ---------------------------------------------------------------------------
// K3 v8: stats heads 32..63 = rolling-window 5x5 dwconv (f32) fused with
// f16 MFMA GRAM (pkrtz split). Each input row loaded ONCE; out[5][8]
// rotating slots; finalize -> affine -> relu(k) -> f16 hi/lo -> 5 MFMAs.
// No LDS, no barriers. grid (32 hp, 2 ysb, 16 b) = 1024 blocks.
// ---------------------------------------------------------------------------
__global__ __launch_bounds__(256) void attn_stats_dw(
    const float* __restrict__ KV,
    const float* __restrict__ dww, const float* __restrict__ dwb,
    const float* __restrict__ pww, const float* __restrict__ pwb,
    float* __restrict__ stats)
{
    const int hp = blockIdx.x, ysb = blockIdx.y, b = blockIdx.z;
    const int tid = threadIdx.x;
    const int lane = tid & 63, wv = tid >> 6;
    const int c  = lane & 15;
    const int kg = lane >> 4;
    const int creal = hp * 24 + 8 + c;

    float wt[25];
    #pragma unroll
    for (int i = 0; i < 25; i++) wt[i] = dww[creal * 25 + i];
    const float pw = pww[creal];
    const float pb = pw * dwb[creal] + pwb[creal];

    const float* cb = KV + ((size_t)b * 512 + hp * 16 + c) * HW;
    const int ybase = ysb * 32 + wv * 8;

    floatx4 accg = (floatx4)0.f;
    floatx4 accs = (floatx4)0.f;
    half8 ones;
    #pragma unroll
    for (int j = 0; j < 8; j++) ones[j] = (_Float16)1.0f;

    #pragma unroll
    for (int xh = 0; xh < 2; xh++) {
        const int x0 = xh * 32 + kg * 8;
        const float mL = (x0 == 0)  ? 0.f : 1.f;
        const float mR = (x0 == 56) ? 0.f : 1.f;
        const int colL = (x0 == 0)  ? 0  : x0 - 4;
        const int colR = (x0 == 56) ? 56 : x0 + 8;

        float out[5][8] = {};
        #pragma unroll
        for (int li = 0; li < 12; li++) {
            const int ry = ybase + li - 2;
            float4 Q0 = {0,0,0,0}, Q1 = {0,0,0,0}, Q2 = {0,0,0,0}, Q3 = {0,0,0,0};
            if (ry >= 0 && ry < WIMG) {          // wave-uniform
                const float* rp = cb + ry * WIMG;
                Q0 = *reinterpret_cast<const float4*>(rp + colL);
                Q1 = *reinterpret_cast<const float4*>(rp + x0);
                Q2 = *reinterpret_cast<const float4*>(rp + x0 + 4);
                Q3 = *reinterpret_cast<const float4*>(rp + colR);
            }
            float win[12] = {Q0.z * mL, Q0.w * mL,
                             Q1.x, Q1.y, Q1.z, Q1.w,
                             Q2.x, Q2.y, Q2.z, Q2.w,
                             Q3.x * mR, Q3.y * mR};
            // scatter into live output rows lo = li-4..li
            #pragma unroll
            for (int rr = 0; rr < 5; rr++) {
                const int lo = li - rr;
                if (lo >= 0 && lo < 8) {
                    #pragma unroll
                    for (int kx = 0; kx < 5; kx++) {
                        float w5 = wt[rr * 5 + kx];
                        #pragma unroll
                        for (int j = 0; j < 8; j++)
                            out[lo % 5][j] += w5 * win[j + kx];
                    }
                }
            }
            // finalize completed output row lo = li-4
            const int lod = li - 4;
            if (lod >= 0 && lod < 8) {
                float fv[8];
                #pragma unroll
                for (int j = 0; j < 8; j++) {
                    float v = out[lod % 5][j] * pw + pb;
                    float vr = fmaxf(v, 0.f);
                    fv[j] = (c < 8) ? vr : v;    // relu k-channels only
                }
                half8 hib, lob;
                split8_f16(fv, hib, lob);
                accg = __builtin_amdgcn_mfma_f32_16x16x32_f16(hib, hib, accg, 0, 0, 0);
                accg = __builtin_amdgcn_mfma_f32_16x16x32_f16(hib, lob, accg, 0, 0, 0);
                accg = __builtin_amdgcn_mfma_f32_16x16x32_f16(lob, hib, accg, 0, 0, 0);
                accs = __builtin_amdgcn_mfma_f32_16x16x32_f16(hib, ones, accs, 0, 0, 0);
                accs = __builtin_amdgcn_mfma_f32_16x16x32_f16(lob, ones, accs, 0, 0, 0);
                #pragma unroll
                for (int j = 0; j < 8; j++) out[lod % 5][j] = 0.f;
            }
        }
    }

    float* sb = stats + ((size_t)b * 64 + 32 + hp) * 72;
    if (c < 8 && kg >= 2) {
        #pragma unroll
        for (int r = 0; r < 4; r++)
            atomicAdd(sb + ((kg - 2) * 4 + r) * 8 + c, accg[r]);
    }
    if (c == 0 && kg < 2) {
        #pragma unroll
        for (int r = 0; r < 4; r++)
            atomicAdd(sb + 64 + kg * 4 + r, accs[r]);
    }
}

// ---------------------------------------------------------------------------
// K3b v7: Qagg = rolling-window 5x5 dwconv + affine of q channels; each input
// row loaded once, out[5][8] rotating slots, finalize -> 2x float4 store.
// Lane (c=lane&7, g=lane>>3) covers 8 px of channel c; wave = full 64-px row
// x 8 channels. grid (32 hb, 2 ysb, 16 b) = 1024 blocks. Raw out (relu K5).
// ---------------------------------------------------------------------------
__global__ __launch_bounds__(256) void q_dwconv(
    const float* __restrict__ Qf,     // (B,256,HW) packed q
    const float* __restrict__ dww, const float* __restrict__ dwb,
    const float* __restrict__ pww, const float* __restrict__ pwb,
    float* __restrict__ Qagg)         // (B,256,HW) packed dwconv(q)
{
    const int hb = blockIdx.x, ysb = blockIdx.y, b = blockIdx.z;
    const int tid = threadIdx.x;
    const int lane = tid & 63, wv = tid >> 6;
    const int c = lane & 7;
    const int g = lane >> 3;          // 0..7
    const int x0 = g * 8;
    const int creal = hb * 24 + c;

    float wt[25];
    #pragma unroll
    for (int i = 0; i < 25; i++) wt[i] = dww[creal * 25 + i];
    const float pw = pww[creal];
    const float pb = pw * dwb[creal] + pwb[creal];

    const float mL = (x0 == 0)  ? 0.f : 1.f;
    const float mR = (x0 == 56) ? 0.f : 1.f;
    const int colL = (x0 == 0)  ? 0  : x0 - 4;
    const int colR = (x0 == 56) ? 56 : x0 + 8;

    const float* cbase = Qf   + ((size_t)b * 256 + hb * 8 + c) * HW;
    float*       obase = Qagg + ((size_t)b * 256 + hb * 8 + c) * HW;
    const int ybase = ysb * 32 + wv * 8;

    float out[5][8] = {};
    #pragma unroll
    for (int li = 0; li < 12; li++) {
        const int ry = ybase + li - 2;
        float4 Q0 = {0,0,0,0}, Q1 = {0,0,0,0}, Q2 = {0,0,0,0}, Q3 = {0,0,0,0};
        if (ry >= 0 && ry < WIMG) {
            const float* rp = cbase + ry * WIMG;
            Q0 = *reinterpret_cast<const float4*>(rp + colL);
            Q1 = *reinterpret_cast<const float4*>(rp + x0);
            Q2 = *reinterpret_cast<const float4*>(rp + x0 + 4);
            Q3 = *reinterpret_cast<const float4*>(rp + colR);
        }
        float win[12] = {Q0.z * mL, Q0.w * mL,
                         Q1.x, Q1.y, Q1.z, Q1.w,
                         Q2.x, Q2.y, Q2.z, Q2.w,
                         Q3.x * mR, Q3.y * mR};
        #pragma unroll
        for (int rr = 0; rr < 5; rr++) {
            const int lo = li - rr;
            if (lo >= 0 && lo < 8) {
                #pragma unroll
                for (int kx = 0; kx < 5; kx++) {
                    float w5 = wt[rr * 5 + kx];
                    #pragma unroll
                    for (int j = 0; j < 8; j++)
                        out[lo % 5][j] += w5 * win[j + kx];
                }
            }
        }
        const int lod = li - 4;
        if (lod >= 0 && lod < 8) {
            float4 o0 = {out[lod % 5][0] * pw + pb, out[lod % 5][1] * pw + pb,
                         out[lod % 5][2] * pw + pb, out[lod % 5][3] * pw + pb};
            float4 o1 = {out[lod % 5][4] * pw + pb, out[lod % 5][5] * pw + pb,
                         out[lod % 5][6] * pw + pb, out[lod % 5][7] * pw + pb};
            float* dst = obase + (ybase + lod) * WIMG + x0;
            *reinterpret_cast<float4*>(dst)     = o0;
            *reinterpret_cast<float4*>(dst + 4) = o1;
            #pragma unroll
            for (int j = 0; j < 8; j++) out[lod % 5][j] = 0.f;
        }
    }
}

// ---------------------------------------------------------------------------
// K4 v2: fold proj weights with vk, COLUMN-RESCALED by g_e = ksum_e + eps.
// Parallelized over head-groups: grid (8 hg, 16 b) = 128 blocks.
// ---------------------------------------------------------------------------
__global__ __launch_bounds__(256) void build_M(
    const float* __restrict__ stats,   // (B,64,72)
    const float* __restrict__ projw,   // (256,512)
    _Float16* __restrict__ Mhi,        // (B,256,512)
    _Float16* __restrict__ Mlo)
{
    const int hg = blockIdx.x;         // head group (8 heads)
    const int b  = blockIdx.y;
    const int tid = threadIdx.x;

    __shared__ float svk[8][64];
    __shared__ float sginv[8][8];

    for (int i = tid; i < 8 * 64; i += 256) {
        int h = i >> 6;
        svk[h][i & 63] = stats[((size_t)b * 64 + hg * 8 + h) * 72 + (i & 63)];
    }
    if (tid < 64)
        sginv[tid >> 3][tid & 7] =
            1.0f / (stats[((size_t)b * 64 + hg * 8 + (tid >> 3)) * 72 + 64 + (tid & 7)] + EPS_F);
    __syncthreads();

    const float* wr = projw + (size_t)tid * 512 + hg * 64;
    #pragma unroll
    for (int hh = 0; hh < 8; hh++) {
        float wv[8];
        float4 a0 = *reinterpret_cast<const float4*>(wr + hh * 8);
        float4 a1 = *reinterpret_cast<const float4*>(wr + hh * 8 + 4);
        wv[0]=a0.x; wv[1]=a0.y; wv[2]=a0.z; wv[3]=a0.w;
        wv[4]=a1.x; wv[5]=a1.y; wv[6]=a1.z; wv[7]=a1.w;
        union { _Float16 h8[8]; uint4 u; } hi, lo;
        #pragma unroll
        for (int e = 0; e < 8; e++) {
            float s = 0.f;
            #pragma unroll
            for (int d = 0; d < 8; d++) s += wv[d] * svk[hh][d * 8 + e];
            s *= sginv[hh][e];
            _Float16 sh = (_Float16)s;
            hi.h8[e] = sh;
            lo.h8[e] = (_Float16)(s - (float)sh);
        }
        size_t off = ((size_t)b * 256 + tid) * 512 + hg * 64 + hh * 8;
        *reinterpret_cast<uint4*>(Mhi + off) = hi.u;
        *reinterpret_cast<uint4*>(Mlo + off) = lo.u;
    }
}

// ---------------------------------------------------------------------------
// K5: 128-px tile, 4 barriers total. Qt_e = QSCALE*g_e*q_e/den (bounded),
// f16; two half-K phases (heads 0..31 from Qf, 32..63 from Qagg), each a
// 2-pass hi/lo f16 MFMA GEMM (256ch x 128px). LDS ~70 KB -> 2 blocks/CU.
// ---------------------------------------------------------------------------
__global__ __launch_bounds__(256) void attn_proj_mfma(
    const float* __restrict__ Qf,      // (B,256,HW) packed q (>=0)
    const float* __restrict__ Qagg,    // (B,256,HW) packed dwconv(q), raw
    const float* __restrict__ stats,   // ksum at [64..71]
    const _Float16* __restrict__ Mhi,  // (B,256,512)
    const _Float16* __restrict__ Mlo,
    const float* __restrict__ scale, const float* __restrict__ bias,
    float* __restrict__ out)           // (B,256,HW)
{
    const int pt  = blockIdx.x * 128;
    const int b   = blockIdx.y;
    const int tid = threadIdx.x;
    const int wv  = tid >> 6, lane = tid & 63;

    __shared__ _Float16 Qt[128][264];     // 67.6 KB half-K [px][k]
    __shared__ float    ksums[64][8];     // 2 KB

    for (int i = tid; i < 512; i += 256)
        ksums[i >> 3][i & 7] = stats[((size_t)b * 64 + (i >> 3)) * 72 + 64 + (i & 7)];
    __syncthreads();

    const int pxl = tid & 127;            // local pixel for Qt build
    const int eg  = (tid >> 7) * 4;       // 4 e's per thread
    const int u = lane & 15, q8 = (lane >> 4) * 8;
    const int quad = lane >> 4;

    floatx4 acc[4][8];
    #pragma unroll
    for (int i = 0; i < 4; i++)
        #pragma unroll
        for (int j = 0; j < 8; j++) acc[i][j] = (floatx4)0.f;

    // ============ phase A: heads 0..31 (q direct from Qf, >=0) ============
    for (int h = 0; h < 32; h++) {
        const float* qp = Qf + ((size_t)b * 256 + h * 8) * HW + pt + pxl;
        float qv[8];
        #pragma unroll
        for (int e = 0; e < 8; e++) qv[e] = qp[(size_t)e * HW];
        float den = EPS_F;
        #pragma unroll
        for (int e = 0; e < 8; e++) den += ksums[h][e] * qv[e];
        float rd = QSCALE / den;
        union { _Float16 h4[4]; uint2 u2; } pk;
        #pragma unroll
        for (int j = 0; j < 4; j++) {
            float g = ksums[h][eg + j] + EPS_F;
            pk.h4[j] = (_Float16)fminf(qv[eg + j] * g * rd, 60000.f);
        }
        *reinterpret_cast<uint2*>(&Qt[pxl][h * 8 + eg]) = pk.u2;
    }
    __syncthreads();

    for (int ks = 0; ks < 8; ks++) {
        half8 ah[4], al[4], bf[8];
        #pragma unroll
        for (int mt = 0; mt < 4; mt++) {
            size_t moff = ((size_t)b * 256 + wv * 64 + mt * 16 + u) * 512 + ks * 32 + q8;
            ah[mt] = *reinterpret_cast<const half8*>(Mhi + moff);
            al[mt] = *reinterpret_cast<const half8*>(Mlo + moff);
        }
        #pragma unroll
        for (int nt = 0; nt < 8; nt++)
            bf[nt] = *reinterpret_cast<const half8*>(&Qt[nt * 16 + u][ks * 32 + q8]);
        #pragma unroll
        for (int mt = 0; mt < 4; mt++)
            #pragma unroll
            for (int nt = 0; nt < 8; nt++) {
                acc[mt][nt] = __builtin_amdgcn_mfma_f32_16x16x32_f16(ah[mt], bf[nt], acc[mt][nt], 0, 0, 0);
                acc[mt][nt] = __builtin_amdgcn_mfma_f32_16x16x32_f16(al[mt], bf[nt], acc[mt][nt], 0, 0, 0);
            }
    }
    __syncthreads();

    // ============ phase B: heads 32..63 (q from Qagg, needs relu) ==========
    for (int h = 32; h < 64; h++) {
        const int hb = h - 32;
        const float* qp = Qagg + ((size_t)b * 256 + hb * 8) * HW + pt + pxl;
        float qv[8];
        #pragma unroll
        for (int e = 0; e < 8; e++) qv[e] = fmaxf(qp[(size_t)e * HW], 0.f);
        float den = EPS_F;
        #pragma unroll
        for (int e = 0; e < 8; e++) den += ksums[h][e] * qv[e];
        float rd = QSCALE / den;
        union { _Float16 h4[4]; uint2 u2; } pk;
        #pragma unroll
        for (int j = 0; j < 4; j++) {
            float g = ksums[h][eg + j] + EPS_F;
            pk.h4[j] = (_Float16)fminf(qv[eg + j] * g * rd, 60000.f);
        }
        *reinterpret_cast<uint2*>(&Qt[pxl][hb * 8 + eg]) = pk.u2;
    }
    __syncthreads();

    for (int ks = 0; ks < 8; ks++) {
        half8 ah[4], al[4], bf[8];
        #pragma unroll
        for (int mt = 0; mt < 4; mt++) {
            size_t moff = ((size_t)b * 256 + wv * 64 + mt * 16 + u) * 512 + 256 + ks * 32 + q8;
            ah[mt] = *reinterpret_cast<const half8*>(Mhi + moff);
            al[mt] = *reinterpret_cast<const half8*>(Mlo + moff);
        }
        #pragma unroll
        for (int nt = 0; nt < 8; nt++)
            bf[nt] = *reinterpret_cast<const half8*>(&Qt[nt * 16 + u][ks * 32 + q8]);
        #pragma unroll
        for (int mt = 0; mt < 4; mt++)
            #pragma unroll
            for (int nt = 0; nt < 8; nt++) {
                acc[mt][nt] = __builtin_amdgcn_mfma_f32_16x16x32_f16(ah[mt], bf[nt], acc[mt][nt], 0, 0, 0);
                acc[mt][nt] = __builtin_amdgcn_mfma_f32_16x16x32_f16(al[mt], bf[nt], acc[mt][nt], 0, 0, 0);
            }
    }

    #pragma unroll
    for (int mt = 0; mt < 4; mt++)
        #pragma unroll
        for (int r = 0; r < 4; r++) {
            int c = wv * 64 + mt * 16 + quad * 4 + r;
            float s = scale[c] * (1.0f / QSCALE);
            float bi = bias[c];
            #pragma unroll
            for (int nt = 0; nt < 8; nt++) {
                int px = pt + nt * 16 + u;
                out[((size_t)b * COUT + c) * HW + px] = fmaxf(acc[mt][nt][r] * s + bi, 0.f);
            }
        }
}

// ---------------------------------------------------------------------------
extern "C" void kernel_launch(void* const* d_in, const int* in_sizes, int n_in,
                              void* d_out, int out_size, void* d_ws, size_t ws_size,
                              hipStream_t stream)
{
    const float* x      = (const float*)d_in[0];
    const float* qkv_w  = (const float*)d_in[1];
    const float* qkv_s  = (const float*)d_in[2];
    const float* qkv_b  = (const float*)d_in[3];
    const float* dw_w   = (const float*)d_in[4];
    const float* dw_b   = (const float*)d_in[5];
    const float* pw_w   = (const float*)d_in[6];
    const float* pw_b   = (const float*)d_in[7];
    const float* proj_w = (const float*)d_in[8];
    const float* proj_s = (const float*)d_in[9];
    const float* proj_b = (const float*)d_in[10];
    float* out = (float*)d_out;

    // ws layout (exactly the PROVEN 192.3 MiB):
    //   [0,128 MiB)    KV f32 — dead after K2/K3; reused: Mhi(4)+Mlo(4)+Qagg(64)
    //   [128,192 MiB)  Qf f32
    //   [192 MiB,+288K) stats
    float*    KV    = (float*)d_ws;
    _Float16* Mhi   = (_Float16*)d_ws;                          // +0
    _Float16* Mlo   = Mhi + (size_t)BATCH * 256 * 512;          // +4 MiB
    float*    Qagg  = (float*)(Mlo + (size_t)BATCH * 256 * 512);// +8 MiB (64 MiB)
    float*    Qf    = KV + (size_t)BATCH * 512 * HW;            // +128 MiB
    float*    stats = Qf + (size_t)BATCH * 256 * HW;            // +192 MiB

    conv_q_f32<<<dim3(HW / 128, 2, BATCH), 256, 0, stream>>>(
        x, qkv_w, qkv_s, qkv_b, Qf);

    conv_kv_mfma<<<dim3(4, 32, BATCH), 256, 0, stream>>>(
        x, qkv_w, qkv_s, qkv_b, KV);

    // zero stats before the atomic-reduce stats kernels
    zero_stats<<<dim3((BATCH * 64 * 72 + 255) / 256), 256, 0, stream>>>(stats);

    attn_stats_direct<<<dim3(32, 4, BATCH), 256, 0, stream>>>(KV, stats);

    attn_stats_dw<<<dim3(32, 2, BATCH), 256, 0, stream>>>(
        KV, dw_w, dw_b, pw_w, pw_b, stats);

    // after K2/K3: KV region dead -> safe to overwrite with Qagg / M
    q_dwconv<<<dim3(32, 2, BATCH), 256, 0, stream>>>(
        Qf, dw_w, dw_b, pw_w, pw_b, Qagg);

    build_M<<<dim3(8, BATCH), 256, 0, stream>>>(stats, proj_w, Mhi, Mlo);

    attn_proj_mfma<<<dim3(HW / 128, BATCH), 256, 0, stream>>>(
        Qf, Qagg, stats, Mhi, Mlo, proj_s, proj_b, out);
}